// Round 1
// baseline (925.082 us; speedup 1.0000x reference)
//
#include <hip/hip_runtime.h>

typedef unsigned short u16;
typedef unsigned int u32;
typedef __attribute__((ext_vector_type(8))) short s16x8;
typedef __attribute__((ext_vector_type(4))) float f32x4;
typedef __attribute__((ext_vector_type(4))) int i32x4;

// ---------- bf16 helpers (bit-level, RNE) ----------
static __device__ __forceinline__ float bf2f(u16 u) {
    return __uint_as_float(((u32)u) << 16);
}
static __device__ __forceinline__ u16 f2bf(float f) {
    u32 x = __float_as_uint(f);
    return (u16)((x + 0x7fffu + ((x >> 16) & 1u)) >> 16);
}
static __device__ __forceinline__ float wave_sum(float v) {
#pragma unroll
    for (int off = 32; off > 0; off >>= 1) v += __shfl_xor(v, off);
    return v;
}

// ---------- adaLN: mod = silu(c) @ ada_w.T + ada_b ----------
__global__ __launch_bounds__(256) void ada_gemm(const float* __restrict__ c,
                                                const float* __restrict__ adaw,
                                                const float* __restrict__ adab,
                                                float* __restrict__ mod) {
    int wid = blockIdx.x * 4 + (threadIdx.x >> 6);  // 0..6911 (output idx)
    int lane = threadIdx.x & 63;
    float sum = 0.f;
#pragma unroll
    for (int i = 0; i < 12; ++i) {
        float cv = c[i * 64 + lane];
        cv = cv / (1.f + __expf(-cv));  // silu
        sum += cv * adaw[(size_t)wid * 768 + i * 64 + lane];
    }
    sum = wave_sum(sum);
    if (lane == 0) mod[wid] = sum + adab[wid];
}

// ---------- fused RMSNorm + modulate, writes bf16 ----------
__global__ __launch_bounds__(256) void rms_mod(const float* __restrict__ x,
                                               const float* __restrict__ w,
                                               const float* __restrict__ mod, int chunk,
                                               u16* __restrict__ out) {
    const int row = blockIdx.x;
    const int tid = threadIdx.x;
    const float* xr = x + (size_t)row * 768;
    float v0 = xr[tid], v1 = xr[256 + tid], v2 = xr[512 + tid];
    float ss = wave_sum(v0 * v0 + v1 * v1 + v2 * v2);
    __shared__ float red[4];
    if ((tid & 63) == 0) red[tid >> 6] = ss;
    __syncthreads();
    float rn = rsqrtf((red[0] + red[1] + red[2] + red[3]) * (1.f / 768.f) + 1e-6f);
    const float* sh = mod + chunk * 768;
    const float* sc = sh + 768;
    u16* orow = out + (size_t)row * 768;
    orow[tid]       = f2bf(v0 * rn * w[tid]       * (1.f + sc[tid])       + sh[tid]);
    orow[256 + tid] = f2bf(v1 * rn * w[256 + tid] * (1.f + sc[256 + tid]) + sh[256 + tid]);
    orow[512 + tid] = f2bf(v2 * rn * w[512 + tid] * (1.f + sc[512 + tid]) + sh[512 + tid]);
}

// ---------- plain RMSNorm (cond), fp32 out ----------
__global__ __launch_bounds__(256) void rms_plain(const float* __restrict__ x,
                                                 const float* __restrict__ w,
                                                 float* __restrict__ out) {
    const int row = blockIdx.x;
    const int tid = threadIdx.x;
    const float* xr = x + (size_t)row * 768;
    float v0 = xr[tid], v1 = xr[256 + tid], v2 = xr[512 + tid];
    float ss = wave_sum(v0 * v0 + v1 * v1 + v2 * v2);
    __shared__ float red[4];
    if ((tid & 63) == 0) red[tid >> 6] = ss;
    __syncthreads();
    float rn = rsqrtf((red[0] + red[1] + red[2] + red[3]) * (1.f / 768.f) + 1e-6f);
    float* orow = out + (size_t)row * 768;
    orow[tid]       = v0 * rn * w[tid];
    orow[256 + tid] = v1 * rn * w[256 + tid];
    orow[512 + tid] = v2 * rn * w[512 + tid];
}

// ---------- MFMA bf16 GEMM:  C[M,N] = A[M,K](bf16) @ W[N,K](f32->bf16)^T ----------
// EPI 0: store f32.  2: out = resid + gate[col]*(acc + bias[col]) (f32).
// 3: store bf16(silu(acc)).  4: outb[idx] = bf16(acc * bf2f(outb[idx])).
template <int EPI>
__global__ __launch_bounds__(256) void gemm_bt(const u16* __restrict__ A,
                                               const float* __restrict__ W,
                                               int M, int N, int K,
                                               float* outf, u16* outb,
                                               const float* resid,
                                               const float* __restrict__ gate,
                                               const float* __restrict__ bias) {
    __shared__ __align__(16) short As[128 * 32];
    __shared__ __align__(16) short Bs[128 * 32];
    const int tid = threadIdx.x;
    const int lane = tid & 63;
    const int w = tid >> 6;
    const int wr = w >> 1, wc = w & 1;
    const int row0 = blockIdx.y * 128, col0 = blockIdx.x * 128;
    f32x4 acc[4][4];
#pragma unroll
    for (int m = 0; m < 4; ++m)
#pragma unroll
        for (int n = 0; n < 4; ++n) acc[m][n] = (f32x4){0.f, 0.f, 0.f, 0.f};

    for (int k0 = 0; k0 < K; k0 += 32) {
        __syncthreads();  // protect previous iteration's reads
        int u = tid;
#pragma unroll
        for (int rep = 0; rep < 2; ++rep, u += 256) {  // 512 16B-units per tile
            int r = u >> 2, seg = u & 3;
            // A: already bf16, direct 16B copy
            const u16* asrc = A + (size_t)(row0 + r) * K + k0 + seg * 8;
            *(i32x4*)&As[u * 8] = *(const i32x4*)asrc;
            // W: fp32 -> bf16 convert during staging
            const float* wsrc = W + (size_t)(col0 + r) * K + k0 + seg * 8;
            float4 w0 = *(const float4*)wsrc;
            float4 w1 = *(const float4*)(wsrc + 4);
            u32 p0 = (u32)f2bf(w0.x) | ((u32)f2bf(w0.y) << 16);
            u32 p1 = (u32)f2bf(w0.z) | ((u32)f2bf(w0.w) << 16);
            u32 p2 = (u32)f2bf(w1.x) | ((u32)f2bf(w1.y) << 16);
            u32 p3 = (u32)f2bf(w1.z) | ((u32)f2bf(w1.w) << 16);
            *(i32x4*)&Bs[u * 8] = (i32x4){(int)p0, (int)p1, (int)p2, (int)p3};
        }
        __syncthreads();
        s16x8 af[4], bfr[4];
#pragma unroll
        for (int m = 0; m < 4; ++m)
            af[m] = *(const s16x8*)&As[(wr * 64 + m * 16 + (lane & 15)) * 32 + (lane >> 4) * 8];
#pragma unroll
        for (int n = 0; n < 4; ++n)
            bfr[n] = *(const s16x8*)&Bs[(wc * 64 + n * 16 + (lane & 15)) * 32 + (lane >> 4) * 8];
#pragma unroll
        for (int m = 0; m < 4; ++m)
#pragma unroll
            for (int n = 0; n < 4; ++n)
                acc[m][n] = __builtin_amdgcn_mfma_f32_16x16x32_bf16(af[m], bfr[n], acc[m][n], 0, 0, 0);
    }
    // epilogue: C[row,col], row=(lane>>4)*4+i, col=lane&15 within each 16x16 frag (HW-verified map)
#pragma unroll
    for (int m = 0; m < 4; ++m) {
#pragma unroll
        for (int n = 0; n < 4; ++n) {
#pragma unroll
            for (int i = 0; i < 4; ++i) {
                int r = row0 + wr * 64 + m * 16 + (lane >> 4) * 4 + i;
                int cc = col0 + wc * 64 + n * 16 + (lane & 15);
                size_t idx = (size_t)r * N + cc;
                float v = acc[m][n][i];
                if constexpr (EPI == 0) {
                    outf[idx] = v;
                } else if constexpr (EPI == 2) {
                    float b = bias ? bias[cc] : 0.f;
                    outf[idx] = resid[idx] + gate[cc] * (v + b);
                } else if constexpr (EPI == 3) {
                    outb[idx] = f2bf(v / (1.f + __expf(-v)));  // silu
                } else if constexpr (EPI == 4) {
                    outb[idx] = f2bf(v * bf2f(outb[idx]));
                }
            }
        }
    }
}

// ---------- SA q/k: RMSNorm(head) + RoPE, in place on qkv f32 ----------
__global__ __launch_bounds__(256) void saqk_rmsrope(float* __restrict__ qkv,
                                                    const float* __restrict__ qnw,
                                                    const float* __restrict__ knw,
                                                    const float* __restrict__ cosT,
                                                    const float* __restrict__ sinT) {
    int wid = blockIdx.x * 4 + (threadIdx.x >> 6);  // 0..49151
    int lane = threadIdx.x & 63;
    int n = wid / 24;
    int rem = wid % 24;
    int which = rem / 12;  // 0=q 1=k
    int h = rem % 12;
    float* p = qkv + (size_t)n * 2304 + which * 768 + h * 64 + lane;
    float v = *p;
    float ss = wave_sum(v * v);
    const float* wv = which ? knw : qnw;
    float vn = v * rsqrtf(ss * (1.f / 64.f) + 1e-6f) * wv[lane];
    float part = __shfl_xor(vn, 32);
    float rot = (lane < 32) ? -part : part;
    *p = vn * cosT[n * 64 + lane] + rot * sinT[n * 64 + lane];
}

// ---------- CA q: RMSNorm + RoPE in place on qbuf [2048][768] ----------
__global__ __launch_bounds__(256) void caq_rmsrope(float* __restrict__ qb,
                                                   const float* __restrict__ qnw,
                                                   const float* __restrict__ cosT,
                                                   const float* __restrict__ sinT) {
    int wid = blockIdx.x * 4 + (threadIdx.x >> 6);  // 0..24575
    int lane = threadIdx.x & 63;
    int n = wid / 12, h = wid % 12;
    float* p = qb + (size_t)n * 768 + h * 64 + lane;
    float v = *p;
    float ss = wave_sum(v * v);
    float vn = v * rsqrtf(ss * (1.f / 64.f) + 1e-6f) * qnw[lane];
    float part = __shfl_xor(vn, 32);
    float rot = (lane < 32) ? -part : part;
    *p = vn * cosT[n * 64 + lane] + rot * sinT[n * 64 + lane];
}

// ---------- CA k: RMSNorm only, in place on kca [16][768] ----------
__global__ __launch_bounds__(256) void cak_rms(float* __restrict__ kca,
                                               const float* __restrict__ knw) {
    int wid = blockIdx.x * 4 + (threadIdx.x >> 6);  // 0..191
    int lane = threadIdx.x & 63;
    int n = wid / 12, h = wid % 12;
    float* p = kca + (size_t)n * 768 + h * 64 + lane;
    float v = *p;
    float ss = wave_sum(v * v);
    *p = v * rsqrtf(ss * (1.f / 64.f) + 1e-6f) * knw[lane];
}

// ---------- CA k/v small GEMM: [16,768] = cn[16,768] @ W[768,768]^T ----------
__global__ __launch_bounds__(256) void small_gemm_nt(const float* __restrict__ cn,
                                                     const float* __restrict__ cakw,
                                                     const float* __restrict__ cavw,
                                                     float* __restrict__ kca,
                                                     float* __restrict__ vca) {
    int wid = blockIdx.x * 4 + (threadIdx.x >> 6);  // 0..24575
    int lane = threadIdx.x & 63;
    int which = wid / 12288;
    int rem = wid % 12288;
    int rrow = rem / 768;
    int ocol = rem % 768;
    const float* Wm = which ? cavw : cakw;
    float sum = 0.f;
#pragma unroll
    for (int i = 0; i < 12; ++i)
        sum += cn[(size_t)rrow * 768 + i * 64 + lane] * Wm[(size_t)ocol * 768 + i * 64 + lane];
    sum = wave_sum(sum);
    if (lane == 0) (which ? vca : kca)[(size_t)rrow * 768 + ocol] = sum;
}

// ---------- SA flash attention (fp32): 64 rows/block, 4 waves split 2048 keys ----------
__global__ __launch_bounds__(256) void sa_attn(const float* __restrict__ qkv,
                                               u16* __restrict__ obuf) {
    const int h = blockIdx.y;
    const int r0 = blockIdx.x * 64;
    const int tid = threadIdx.x;
    const int lane = tid & 63;
    const int w = tid >> 6;
    __shared__ __align__(16) float smem[8704];
    float* kb = smem + w * 2048;  // [16][64]
    float* vb = kb + 1024;
    const int row = r0 + lane;  // each lane owns one query row
    float q[64];
    {
        const float4* qrow = (const float4*)(qkv + (size_t)row * 2304 + h * 64);
#pragma unroll
        for (int d4 = 0; d4 < 16; ++d4) {
            float4 t = qrow[d4];
            q[d4 * 4 + 0] = t.x * 0.125f; q[d4 * 4 + 1] = t.y * 0.125f;
            q[d4 * 4 + 2] = t.z * 0.125f; q[d4 * 4 + 3] = t.w * 0.125f;
        }
    }
    float o[64];
#pragma unroll
    for (int d = 0; d < 64; ++d) o[d] = 0.f;
    float mrun = -1e30f, lrun = 0.f;

    for (int t = 0; t < 32; ++t) {  // 32 tiles x 16 keys = 512 keys per wave
        __syncthreads();
        const int kbase = w * 512 + t * 16;
#pragma unroll
        for (int rep = 0; rep < 4; ++rep) {
            int u = rep * 64 + lane;
            int key = u >> 4, f4 = u & 15;
            const float* base = qkv + (size_t)(kbase + key) * 2304 + 768 + h * 64;
            ((float4*)(kb + key * 64))[f4] = ((const float4*)base)[f4];
            ((float4*)(vb + key * 64))[f4] = ((const float4*)(base + 768))[f4];
        }
        __syncthreads();
        float s[16];
#pragma unroll
        for (int j = 0; j < 16; ++j) {
            const float4* kr = (const float4*)(kb + j * 64);
            float a0 = 0, a1 = 0, a2 = 0, a3 = 0;
#pragma unroll
            for (int d4 = 0; d4 < 16; ++d4) {
                float4 kk = kr[d4];
                a0 += q[d4 * 4 + 0] * kk.x; a1 += q[d4 * 4 + 1] * kk.y;
                a2 += q[d4 * 4 + 2] * kk.z; a3 += q[d4 * 4 + 3] * kk.w;
            }
            s[j] = (a0 + a1) + (a2 + a3);
        }
        float tmax = s[0];
#pragma unroll
        for (int j = 1; j < 16; ++j) tmax = fmaxf(tmax, s[j]);
        float mnew = fmaxf(mrun, tmax);
        float corr = __expf(mrun - mnew);
        lrun *= corr;
#pragma unroll
        for (int d = 0; d < 64; ++d) o[d] *= corr;
#pragma unroll
        for (int j = 0; j < 16; ++j) { s[j] = __expf(s[j] - mnew); lrun += s[j]; }
#pragma unroll
        for (int j = 0; j < 16; ++j) {
            const float4* vr = (const float4*)(vb + j * 64);
            float p = s[j];
#pragma unroll
            for (int d4 = 0; d4 < 16; ++d4) {
                float4 vv = vr[d4];
                o[d4 * 4 + 0] += p * vv.x; o[d4 * 4 + 1] += p * vv.y;
                o[d4 * 4 + 2] += p * vv.z; o[d4 * 4 + 3] += p * vv.w;
            }
        }
        mrun = mnew;
    }
    // ---- cross-wave combine (LDS reused) ----
    __syncthreads();
    float* mArr = smem;        // [4][64]
    float* lArr = smem + 256;  // [4][64]
    u16* ob = (u16*)(smem + 512);  // [256][64] bf16
    mArr[w * 64 + lane] = mrun;
    __syncthreads();
    float Mg = fmaxf(fmaxf(mArr[lane], mArr[64 + lane]),
                     fmaxf(mArr[128 + lane], mArr[192 + lane]));
    float sc = __expf(mrun - Mg);
    lArr[w * 64 + lane] = lrun * sc;
#pragma unroll
    for (int d = 0; d < 64; ++d) ob[(w * 64 + lane) * 64 + d] = f2bf(o[d] * sc);
    __syncthreads();
    int r = tid & 63, cq = tid >> 6;
    float denom = lArr[r] + lArr[64 + r] + lArr[128 + r] + lArr[192 + r];
    float inv = 1.f / denom;
#pragma unroll
    for (int dd = 0; dd < 16; ++dd) {
        int d = cq * 16 + dd;
        float val = bf2f(ob[r * 64 + d]) + bf2f(ob[(64 + r) * 64 + d]) +
                    bf2f(ob[(128 + r) * 64 + d]) + bf2f(ob[(192 + r) * 64 + d]);
        obuf[(size_t)(r0 + r) * 768 + h * 64 + d] = f2bf(val * inv);
    }
}

// ---------- CA attention: 16 keys, one wave per (n,h), lane = dim ----------
__global__ __launch_bounds__(256) void ca_attn(const float* __restrict__ qb,
                                               const float* __restrict__ kca,
                                               const float* __restrict__ vca,
                                               u16* __restrict__ obuf) {
    int wid = blockIdx.x * 4 + (threadIdx.x >> 6);  // 0..24575
    int lane = threadIdx.x & 63;
    int n = wid / 12, h = wid % 12;
    float qd = qb[(size_t)n * 768 + h * 64 + lane] * 0.125f;
    float s[16];
#pragma unroll
    for (int j = 0; j < 16; ++j) {
        float part = qd * kca[(size_t)j * 768 + h * 64 + lane];
        s[j] = wave_sum(part);
    }
    float mm = s[0];
#pragma unroll
    for (int j = 1; j < 16; ++j) mm = fmaxf(mm, s[j]);
    float l = 0.f;
#pragma unroll
    for (int j = 0; j < 16; ++j) { s[j] = __expf(s[j] - mm); l += s[j]; }
    float od = 0.f;
#pragma unroll
    for (int j = 0; j < 16; ++j) od += s[j] * vca[(size_t)j * 768 + h * 64 + lane];
    obuf[(size_t)n * 768 + h * 64 + lane] = f2bf(od / l);
}

// =======================================================================
extern "C" void kernel_launch(void* const* d_in, const int* in_sizes, int n_in,
                              void* d_out, int out_size, void* d_ws, size_t ws_size,
                              hipStream_t stream) {
    const float* x     = (const float*)d_in[0];
    const float* c     = (const float*)d_in[1];
    const float* cond  = (const float*)d_in[2];
    const float* cosT  = (const float*)d_in[3];
    const float* sinT  = (const float*)d_in[4];
    const float* n1w   = (const float*)d_in[5];
    const float* n2w   = (const float*)d_in[6];
    const float* n3w   = (const float*)d_in[7];
    const float* cnw   = (const float*)d_in[8];
    const float* saqkvw  = (const float*)d_in[9];
    const float* saprojw = (const float*)d_in[10];
    const float* saprojb = (const float*)d_in[11];
    const float* saqnw   = (const float*)d_in[12];
    const float* saknw   = (const float*)d_in[13];
    const float* caqw    = (const float*)d_in[14];
    const float* cakw    = (const float*)d_in[15];
    const float* cavw    = (const float*)d_in[16];
    const float* caprojw = (const float*)d_in[17];
    const float* caprojb = (const float*)d_in[18];
    const float* caqnw   = (const float*)d_in[19];
    const float* caknw   = (const float*)d_in[20];
    const float* w1      = (const float*)d_in[21];
    const float* w2      = (const float*)d_in[22];
    const float* w3      = (const float*)d_in[23];
    const float* adaw    = (const float*)d_in[24];
    const float* adab    = (const float*)d_in[25];
    float* out = (float*)d_out;
    char* ws = (char*)d_ws;

    // ws layout (bytes): mod | hbuf(bf16) | obuf(bf16) | R1 (qkv f32 / qbuf f32 / g bf16) | cn | kca | vca
    float* mod = (float*)ws;                               // 6912 f32
    u16* hbuf  = (u16*)(ws + 32768);                       // 2048x768 bf16
    u16* obuf  = (u16*)(ws + 32768 + 3145728);             // 2048x768 bf16
    float* qkv = (float*)(ws + 6324224);                   // 2048x2304 f32
    float* qbuf = qkv;                                     // 2048x768 f32 (reuse)
    u16* gbuf  = (u16*)qkv;                                // 2048x3072 bf16 (reuse)
    float* cn  = (float*)(ws + 25198592);                  // 16x768
    float* kca = (float*)(ws + 25247744);                  // 16x768
    float* vca = (float*)(ws + 25296896);                  // 16x768

    // adaLN
    ada_gemm<<<1728, 256, 0, stream>>>(c, adaw, adab, mod);

    // ---- self-attention ----
    rms_mod<<<2048, 256, 0, stream>>>(x, n1w, mod, 0, hbuf);
    gemm_bt<0><<<dim3(18, 16), 256, 0, stream>>>(hbuf, saqkvw, 2048, 2304, 768,
                                                 qkv, nullptr, nullptr, nullptr, nullptr);
    saqk_rmsrope<<<12288, 256, 0, stream>>>(qkv, saqnw, saknw, cosT, sinT);
    sa_attn<<<dim3(32, 12), 256, 0, stream>>>(qkv, obuf);
    gemm_bt<2><<<dim3(6, 16), 256, 0, stream>>>(obuf, saprojw, 2048, 768, 768,
                                                out, nullptr, x, mod + 2 * 768, saprojb);

    // ---- cross-attention ----
    rms_mod<<<2048, 256, 0, stream>>>(out, n2w, mod, 3, hbuf);
    gemm_bt<0><<<dim3(6, 16), 256, 0, stream>>>(hbuf, caqw, 2048, 768, 768,
                                                qbuf, nullptr, nullptr, nullptr, nullptr);
    rms_plain<<<16, 256, 0, stream>>>(cond, cnw, cn);
    small_gemm_nt<<<6144, 256, 0, stream>>>(cn, cakw, cavw, kca, vca);
    cak_rms<<<48, 256, 0, stream>>>(kca, caknw);
    caq_rmsrope<<<6144, 256, 0, stream>>>(qbuf, caqnw, cosT, sinT);
    ca_attn<<<6144, 256, 0, stream>>>(qbuf, kca, vca, obuf);
    gemm_bt<2><<<dim3(6, 16), 256, 0, stream>>>(obuf, caprojw, 2048, 768, 768,
                                                out, nullptr, out, mod + 5 * 768, caprojb);

    // ---- SwiGLU MLP ----
    rms_mod<<<2048, 256, 0, stream>>>(out, n3w, mod, 6, hbuf);
    gemm_bt<3><<<dim3(24, 16), 256, 0, stream>>>(hbuf, w1, 2048, 3072, 768,
                                                 nullptr, gbuf, nullptr, nullptr, nullptr);
    gemm_bt<4><<<dim3(24, 16), 256, 0, stream>>>(hbuf, w3, 2048, 3072, 768,
                                                 nullptr, gbuf, nullptr, nullptr, nullptr);
    gemm_bt<2><<<dim3(6, 16), 256, 0, stream>>>(gbuf, w2, 2048, 768, 3072,
                                                out, nullptr, out, mod + 8 * 768, nullptr);
}

// Round 2
// 472.608 us; speedup vs baseline: 1.9574x; 1.9574x over previous
//
#include <hip/hip_runtime.h>

typedef unsigned short u16;
typedef unsigned int u32;
typedef __attribute__((ext_vector_type(8))) short s16x8;
typedef __attribute__((ext_vector_type(4))) float f32x4;
typedef __attribute__((ext_vector_type(4))) int i32x4;

// ---------- bf16 helpers (bit-level, RNE) ----------
static __device__ __forceinline__ float bf2f(u16 u) {
    return __uint_as_float(((u32)u) << 16);
}
static __device__ __forceinline__ u16 f2bf(float f) {
    u32 x = __float_as_uint(f);
    return (u16)((x + 0x7fffu + ((x >> 16) & 1u)) >> 16);
}
static __device__ __forceinline__ i32x4 pack8(float4 a, float4 b) {
    u32 p0 = (u32)f2bf(a.x) | ((u32)f2bf(a.y) << 16);
    u32 p1 = (u32)f2bf(a.z) | ((u32)f2bf(a.w) << 16);
    u32 p2 = (u32)f2bf(b.x) | ((u32)f2bf(b.y) << 16);
    u32 p3 = (u32)f2bf(b.z) | ((u32)f2bf(b.w) << 16);
    return (i32x4){(int)p0, (int)p1, (int)p2, (int)p3};
}
static __device__ __forceinline__ float wave_sum(float v) {
#pragma unroll
    for (int off = 32; off > 0; off >>= 1) v += __shfl_xor(v, off);
    return v;
}

// ---------- adaLN: mod = silu(c) @ ada_w.T + ada_b ----------
__global__ __launch_bounds__(256) void ada_gemm(const float* __restrict__ c,
                                                const float* __restrict__ adaw,
                                                const float* __restrict__ adab,
                                                float* __restrict__ mod) {
    int wid = blockIdx.x * 4 + (threadIdx.x >> 6);  // 0..6911 (output idx)
    int lane = threadIdx.x & 63;
    float sum = 0.f;
#pragma unroll
    for (int i = 0; i < 12; ++i) {
        float cv = c[i * 64 + lane];
        cv = cv / (1.f + __expf(-cv));  // silu
        sum += cv * adaw[(size_t)wid * 768 + i * 64 + lane];
    }
    sum = wave_sum(sum);
    if (lane == 0) mod[wid] = sum + adab[wid];
}

// ---------- fused RMSNorm + modulate, writes bf16 ----------
__global__ __launch_bounds__(256) void rms_mod(const float* __restrict__ x,
                                               const float* __restrict__ w,
                                               const float* __restrict__ mod, int chunk,
                                               u16* __restrict__ out) {
    const int row = blockIdx.x;
    const int tid = threadIdx.x;
    const float* xr = x + (size_t)row * 768;
    float v0 = xr[tid], v1 = xr[256 + tid], v2 = xr[512 + tid];
    float ss = wave_sum(v0 * v0 + v1 * v1 + v2 * v2);
    __shared__ float red[4];
    if ((tid & 63) == 0) red[tid >> 6] = ss;
    __syncthreads();
    float rn = rsqrtf((red[0] + red[1] + red[2] + red[3]) * (1.f / 768.f) + 1e-6f);
    const float* sh = mod + chunk * 768;
    const float* sc = sh + 768;
    u16* orow = out + (size_t)row * 768;
    orow[tid]       = f2bf(v0 * rn * w[tid]       * (1.f + sc[tid])       + sh[tid]);
    orow[256 + tid] = f2bf(v1 * rn * w[256 + tid] * (1.f + sc[256 + tid]) + sh[256 + tid]);
    orow[512 + tid] = f2bf(v2 * rn * w[512 + tid] * (1.f + sc[512 + tid]) + sh[512 + tid]);
}

// ---------- plain RMSNorm (cond), fp32 out ----------
__global__ __launch_bounds__(256) void rms_plain(const float* __restrict__ x,
                                                 const float* __restrict__ w,
                                                 float* __restrict__ out) {
    const int row = blockIdx.x;
    const int tid = threadIdx.x;
    const float* xr = x + (size_t)row * 768;
    float v0 = xr[tid], v1 = xr[256 + tid], v2 = xr[512 + tid];
    float ss = wave_sum(v0 * v0 + v1 * v1 + v2 * v2);
    __shared__ float red[4];
    if ((tid & 63) == 0) red[tid >> 6] = ss;
    __syncthreads();
    float rn = rsqrtf((red[0] + red[1] + red[2] + red[3]) * (1.f / 768.f) + 1e-6f);
    float* orow = out + (size_t)row * 768;
    orow[tid]       = v0 * rn * w[tid];
    orow[256 + tid] = v1 * rn * w[256 + tid];
    orow[512 + tid] = v2 * rn * w[512 + tid];
}

// ---------- MFMA bf16 GEMM:  C[M,N] = A[M,K](bf16) @ W[N,K](f32->bf16)^T ----------
// EPI 0: store f32.  2: out = resid + gate[col]*(acc + bias[col]) (f32).
// 3: store bf16(silu(acc)).  4: outb[idx] = bf16(acc * bf2f(outb[idx])).
template <int EPI>
__global__ __launch_bounds__(256) void gemm_bt(const u16* __restrict__ A,
                                               const float* __restrict__ W,
                                               int M, int N, int K,
                                               float* outf, u16* outb,
                                               const float* resid,
                                               const float* __restrict__ gate,
                                               const float* __restrict__ bias) {
    __shared__ __align__(16) short As[128 * 32];
    __shared__ __align__(16) short Bs[128 * 32];
    const int tid = threadIdx.x;
    const int lane = tid & 63;
    const int w = tid >> 6;
    const int wr = w >> 1, wc = w & 1;
    const int row0 = blockIdx.y * 128, col0 = blockIdx.x * 128;
    f32x4 acc[4][4];
#pragma unroll
    for (int m = 0; m < 4; ++m)
#pragma unroll
        for (int n = 0; n < 4; ++n) acc[m][n] = (f32x4){0.f, 0.f, 0.f, 0.f};

    for (int k0 = 0; k0 < K; k0 += 32) {
        __syncthreads();  // protect previous iteration's reads
        int u = tid;
#pragma unroll
        for (int rep = 0; rep < 2; ++rep, u += 256) {  // 512 16B-units per tile
            int r = u >> 2, seg = u & 3;
            // A: already bf16, direct 16B copy
            const u16* asrc = A + (size_t)(row0 + r) * K + k0 + seg * 8;
            *(i32x4*)&As[u * 8] = *(const i32x4*)asrc;
            // W: fp32 -> bf16 convert during staging
            const float* wsrc = W + (size_t)(col0 + r) * K + k0 + seg * 8;
            float4 w0 = *(const float4*)wsrc;
            float4 w1 = *(const float4*)(wsrc + 4);
            *(i32x4*)&Bs[u * 8] = pack8(w0, w1);
        }
        __syncthreads();
        s16x8 af[4], bfr[4];
#pragma unroll
        for (int m = 0; m < 4; ++m)
            af[m] = *(const s16x8*)&As[(wr * 64 + m * 16 + (lane & 15)) * 32 + (lane >> 4) * 8];
#pragma unroll
        for (int n = 0; n < 4; ++n)
            bfr[n] = *(const s16x8*)&Bs[(wc * 64 + n * 16 + (lane & 15)) * 32 + (lane >> 4) * 8];
#pragma unroll
        for (int m = 0; m < 4; ++m)
#pragma unroll
            for (int n = 0; n < 4; ++n)
                acc[m][n] = __builtin_amdgcn_mfma_f32_16x16x32_bf16(af[m], bfr[n], acc[m][n], 0, 0, 0);
    }
    // epilogue: C[row,col], row=(lane>>4)*4+i, col=lane&15 within each 16x16 frag (HW-verified map)
#pragma unroll
    for (int m = 0; m < 4; ++m) {
#pragma unroll
        for (int n = 0; n < 4; ++n) {
#pragma unroll
            for (int i = 0; i < 4; ++i) {
                int r = row0 + wr * 64 + m * 16 + (lane >> 4) * 4 + i;
                int cc = col0 + wc * 64 + n * 16 + (lane & 15);
                size_t idx = (size_t)r * N + cc;
                float v = acc[m][n][i];
                if constexpr (EPI == 0) {
                    outf[idx] = v;
                } else if constexpr (EPI == 2) {
                    float b = bias ? bias[cc] : 0.f;
                    outf[idx] = resid[idx] + gate[cc] * (v + b);
                } else if constexpr (EPI == 3) {
                    outb[idx] = f2bf(v / (1.f + __expf(-v)));  // silu
                } else if constexpr (EPI == 4) {
                    outb[idx] = f2bf(v * bf2f(outb[idx]));
                }
            }
        }
    }
}

// ---------- SA q/k: RMSNorm(head) + RoPE, in place on qkv f32 ----------
__global__ __launch_bounds__(256) void saqk_rmsrope(float* __restrict__ qkv,
                                                    const float* __restrict__ qnw,
                                                    const float* __restrict__ knw,
                                                    const float* __restrict__ cosT,
                                                    const float* __restrict__ sinT) {
    int wid = blockIdx.x * 4 + (threadIdx.x >> 6);  // 0..49151
    int lane = threadIdx.x & 63;
    int n = wid / 24;
    int rem = wid % 24;
    int which = rem / 12;  // 0=q 1=k
    int h = rem % 12;
    float* p = qkv + (size_t)n * 2304 + which * 768 + h * 64 + lane;
    float v = *p;
    float ss = wave_sum(v * v);
    const float* wv = which ? knw : qnw;
    float vn = v * rsqrtf(ss * (1.f / 64.f) + 1e-6f) * wv[lane];
    float part = __shfl_xor(vn, 32);
    float rot = (lane < 32) ? -part : part;
    *p = vn * cosT[n * 64 + lane] + rot * sinT[n * 64 + lane];
}

// ---------- CA q: RMSNorm + RoPE in place on qbuf [2048][768] ----------
__global__ __launch_bounds__(256) void caq_rmsrope(float* __restrict__ qb,
                                                   const float* __restrict__ qnw,
                                                   const float* __restrict__ cosT,
                                                   const float* __restrict__ sinT) {
    int wid = blockIdx.x * 4 + (threadIdx.x >> 6);  // 0..24575
    int lane = threadIdx.x & 63;
    int n = wid / 12, h = wid % 12;
    float* p = qb + (size_t)n * 768 + h * 64 + lane;
    float v = *p;
    float ss = wave_sum(v * v);
    float vn = v * rsqrtf(ss * (1.f / 64.f) + 1e-6f) * qnw[lane];
    float part = __shfl_xor(vn, 32);
    float rot = (lane < 32) ? -part : part;
    *p = vn * cosT[n * 64 + lane] + rot * sinT[n * 64 + lane];
}

// ---------- CA k: RMSNorm only, in place on kca [16][768] ----------
__global__ __launch_bounds__(256) void cak_rms(float* __restrict__ kca,
                                               const float* __restrict__ knw) {
    int wid = blockIdx.x * 4 + (threadIdx.x >> 6);  // 0..191
    int lane = threadIdx.x & 63;
    int n = wid / 12, h = wid % 12;
    float* p = kca + (size_t)n * 768 + h * 64 + lane;
    float v = *p;
    float ss = wave_sum(v * v);
    *p = v * rsqrtf(ss * (1.f / 64.f) + 1e-6f) * knw[lane];
}

// ---------- CA k/v small GEMM: [16,768] = cn[16,768] @ W[768,768]^T ----------
__global__ __launch_bounds__(256) void small_gemm_nt(const float* __restrict__ cn,
                                                     const float* __restrict__ cakw,
                                                     const float* __restrict__ cavw,
                                                     float* __restrict__ kca,
                                                     float* __restrict__ vca) {
    int wid = blockIdx.x * 4 + (threadIdx.x >> 6);  // 0..24575
    int lane = threadIdx.x & 63;
    int which = wid / 12288;
    int rem = wid % 12288;
    int rrow = rem / 768;
    int ocol = rem % 768;
    const float* Wm = which ? cavw : cakw;
    float sum = 0.f;
#pragma unroll
    for (int i = 0; i < 12; ++i)
        sum += cn[(size_t)rrow * 768 + i * 64 + lane] * Wm[(size_t)ocol * 768 + i * 64 + lane];
    sum = wave_sum(sum);
    if (lane == 0) (which ? vca : kca)[(size_t)rrow * 768 + ocol] = sum;
}

// ---------- SA flash attention, MFMA bf16 ----------
// Block: head h = blockIdx.y, 64 q-rows (blockIdx.x). 4 waves x 16 q-rows.
// Loop over 32 tiles of 64 keys. K staged [64k][64d] bf16 swizzled; V staged
// transposed [64d][64k] bf16 swizzled. Online softmax per q-row in registers
// (16-lane-group shuffle reduces). P relayout through per-wave swizzled LDS.
__global__ __launch_bounds__(256) void sa_attn_mfma(const float* __restrict__ qkv,
                                                    u16* __restrict__ obuf) {
    const int h = blockIdx.y;
    const int r0 = blockIdx.x * 64;
    const int tid = threadIdx.x;
    const int lane = tid & 63;
    const int w = tid >> 6;
    __shared__ __align__(16) u16 Ks[64 * 64];
    __shared__ __align__(16) u16 Vt[64 * 64];
    __shared__ __align__(16) u16 Ps[4][16 * 64];

    // Q fragments (A-operand): row = lane&15 within wave's 16 rows, pre-scaled
    s16x8 qf[2];
    {
        const float* qrow = qkv + (size_t)(r0 + w * 16 + (lane & 15)) * 2304 + h * 64 + ((lane >> 4) * 8);
#pragma unroll
        for (int kk = 0; kk < 2; ++kk) {
            float4 a = *(const float4*)(qrow + kk * 32);
            float4 b = *(const float4*)(qrow + kk * 32 + 4);
            a.x *= 0.125f; a.y *= 0.125f; a.z *= 0.125f; a.w *= 0.125f;
            b.x *= 0.125f; b.y *= 0.125f; b.z *= 0.125f; b.w *= 0.125f;
            i32x4 p = pack8(a, b);
            qf[kk] = *(s16x8*)&p;
        }
    }
    f32x4 oacc[4];
#pragma unroll
    for (int n = 0; n < 4; ++n) oacc[n] = (f32x4){0.f, 0.f, 0.f, 0.f};
    float mrun[4] = {-1e30f, -1e30f, -1e30f, -1e30f};
    float lp[4] = {0.f, 0.f, 0.f, 0.f};

    const int key_s = tid >> 2;           // staging: 4 threads per key row
    const int dseg = (tid & 3) * 16;

    for (int t = 0; t < 32; ++t) {
        __syncthreads();  // protect Ks/Vt from previous iteration's readers
        // ---- stage K tile [64][64] and V^T tile [64][64] (fp32 -> bf16) ----
        {
            const float* kbase = qkv + (size_t)(t * 64 + key_s) * 2304 + 768 + h * 64 + dseg;
#pragma unroll
            for (int half = 0; half < 2; ++half) {
                float4 a = *(const float4*)(kbase + half * 8);
                float4 b = *(const float4*)(kbase + half * 8 + 4);
                int d = dseg + half * 8;
                int boff = key_s * 128 + ((d * 2) ^ ((key_s & 7) << 4));
                *(i32x4*)((char*)Ks + boff) = pack8(a, b);
            }
            const float* vbase = kbase + 768;
#pragma unroll
            for (int q4 = 0; q4 < 4; ++q4) {
                float4 a = *(const float4*)(vbase + q4 * 4);
#pragma unroll
                for (int j = 0; j < 4; ++j) {
                    int d = dseg + q4 * 4 + j;
                    int boff = d * 128 + ((key_s * 2) ^ ((d & 7) << 4));
                    *(u16*)((char*)Vt + boff) = f2bf(((const float*)&a)[j]);
                }
            }
        }
        __syncthreads();
        // ---- QK^T: S[16 rows][64 keys] per wave ----
        f32x4 sacc[4];
#pragma unroll
        for (int n = 0; n < 4; ++n) sacc[n] = (f32x4){0.f, 0.f, 0.f, 0.f};
#pragma unroll
        for (int kk = 0; kk < 2; ++kk) {
#pragma unroll
            for (int n = 0; n < 4; ++n) {
                int key = n * 16 + (lane & 15);
                int d = kk * 32 + (lane >> 4) * 8;
                int boff = key * 128 + ((d * 2) ^ ((key & 7) << 4));
                s16x8 kf = *(const s16x8*)((const char*)Ks + boff);
                sacc[n] = __builtin_amdgcn_mfma_f32_16x16x32_bf16(qf[kk], kf, sacc[n], 0, 0, 0);
            }
        }
        // ---- online softmax (rows = (lane>>4)*4 + i; keys spread over 16-lane group) ----
        float tmax[4];
#pragma unroll
        for (int i = 0; i < 4; ++i)
            tmax[i] = fmaxf(fmaxf(sacc[0][i], sacc[1][i]), fmaxf(sacc[2][i], sacc[3][i]));
#pragma unroll
        for (int off = 1; off < 16; off <<= 1) {
#pragma unroll
            for (int i = 0; i < 4; ++i) tmax[i] = fmaxf(tmax[i], __shfl_xor(tmax[i], off));
        }
        float corr[4];
#pragma unroll
        for (int i = 0; i < 4; ++i) {
            float mn = fmaxf(mrun[i], tmax[i]);
            corr[i] = __expf(mrun[i] - mn);
            mrun[i] = mn;
            lp[i] *= corr[i];
        }
#pragma unroll
        for (int n = 0; n < 4; ++n) {
#pragma unroll
            for (int i = 0; i < 4; ++i) oacc[n][i] *= corr[i];
        }
        // exp + stash P (bf16) into per-wave swizzled LDS for A-operand relayout
#pragma unroll
        for (int n = 0; n < 4; ++n) {
#pragma unroll
            for (int i = 0; i < 4; ++i) {
                float p = __expf(sacc[n][i] - mrun[i]);
                lp[i] += p;
                int row = (lane >> 4) * 4 + i;
                int key = n * 16 + (lane & 15);
                int boff = row * 128 + ((key * 2) ^ ((row & 7) << 4));
                *(u16*)((char*)Ps[w] + boff) = f2bf(p);
            }
        }
        // ---- PV: O += P[16][64] @ V[64 keys][64 d]  (B = Vt[d][key]) ----
#pragma unroll
        for (int ks = 0; ks < 2; ++ks) {
            int prow = lane & 15;
            int koff = ks * 32 + (lane >> 4) * 8;
            int pboff = prow * 128 + ((koff * 2) ^ ((prow & 7) << 4));
            s16x8 pf = *(const s16x8*)((const char*)Ps[w] + pboff);
#pragma unroll
            for (int n = 0; n < 4; ++n) {
                int d = n * 16 + (lane & 15);
                int vboff = d * 128 + ((koff * 2) ^ ((d & 7) << 4));
                s16x8 vf = *(const s16x8*)((const char*)Vt + vboff);
                oacc[n] = __builtin_amdgcn_mfma_f32_16x16x32_bf16(pf, vf, oacc[n], 0, 0, 0);
            }
        }
    }
    // ---- finalize: reduce row-sums across 16-lane group, normalize, store ----
#pragma unroll
    for (int off = 1; off < 16; off <<= 1) {
#pragma unroll
        for (int i = 0; i < 4; ++i) lp[i] += __shfl_xor(lp[i], off);
    }
#pragma unroll
    for (int i = 0; i < 4; ++i) lp[i] = 1.f / lp[i];
#pragma unroll
    for (int n = 0; n < 4; ++n) {
#pragma unroll
        for (int i = 0; i < 4; ++i) {
            int r = r0 + w * 16 + (lane >> 4) * 4 + i;
            int d = n * 16 + (lane & 15);
            obuf[(size_t)r * 768 + h * 64 + d] = f2bf(oacc[n][i] * lp[i]);
        }
    }
}

// ---------- CA attention: 16 keys, one wave per (n,h), lane = dim ----------
__global__ __launch_bounds__(256) void ca_attn(const float* __restrict__ qb,
                                               const float* __restrict__ kca,
                                               const float* __restrict__ vca,
                                               u16* __restrict__ obuf) {
    int wid = blockIdx.x * 4 + (threadIdx.x >> 6);  // 0..24575
    int lane = threadIdx.x & 63;
    int n = wid / 12, h = wid % 12;
    float qd = qb[(size_t)n * 768 + h * 64 + lane] * 0.125f;
    float s[16];
#pragma unroll
    for (int j = 0; j < 16; ++j) {
        float part = qd * kca[(size_t)j * 768 + h * 64 + lane];
        s[j] = wave_sum(part);
    }
    float mm = s[0];
#pragma unroll
    for (int j = 1; j < 16; ++j) mm = fmaxf(mm, s[j]);
    float l = 0.f;
#pragma unroll
    for (int j = 0; j < 16; ++j) { s[j] = __expf(s[j] - mm); l += s[j]; }
    float od = 0.f;
#pragma unroll
    for (int j = 0; j < 16; ++j) od += s[j] * vca[(size_t)j * 768 + h * 64 + lane];
    obuf[(size_t)n * 768 + h * 64 + lane] = f2bf(od / l);
}

// =======================================================================
extern "C" void kernel_launch(void* const* d_in, const int* in_sizes, int n_in,
                              void* d_out, int out_size, void* d_ws, size_t ws_size,
                              hipStream_t stream) {
    const float* x     = (const float*)d_in[0];
    const float* c     = (const float*)d_in[1];
    const float* cond  = (const float*)d_in[2];
    const float* cosT  = (const float*)d_in[3];
    const float* sinT  = (const float*)d_in[4];
    const float* n1w   = (const float*)d_in[5];
    const float* n2w   = (const float*)d_in[6];
    const float* n3w   = (const float*)d_in[7];
    const float* cnw   = (const float*)d_in[8];
    const float* saqkvw  = (const float*)d_in[9];
    const float* saprojw = (const float*)d_in[10];
    const float* saprojb = (const float*)d_in[11];
    const float* saqnw   = (const float*)d_in[12];
    const float* saknw   = (const float*)d_in[13];
    const float* caqw    = (const float*)d_in[14];
    const float* cakw    = (const float*)d_in[15];
    const float* cavw    = (const float*)d_in[16];
    const float* caprojw = (const float*)d_in[17];
    const float* caprojb = (const float*)d_in[18];
    const float* caqnw   = (const float*)d_in[19];
    const float* caknw   = (const float*)d_in[20];
    const float* w1      = (const float*)d_in[21];
    const float* w2      = (const float*)d_in[22];
    const float* w3      = (const float*)d_in[23];
    const float* adaw    = (const float*)d_in[24];
    const float* adab    = (const float*)d_in[25];
    float* out = (float*)d_out;
    char* ws = (char*)d_ws;

    // ws layout (bytes): mod | hbuf(bf16) | obuf(bf16) | R1 (qkv f32 / qbuf f32 / g bf16) | cn | kca | vca
    float* mod = (float*)ws;                               // 6912 f32
    u16* hbuf  = (u16*)(ws + 32768);                       // 2048x768 bf16
    u16* obuf  = (u16*)(ws + 32768 + 3145728);             // 2048x768 bf16
    float* qkv = (float*)(ws + 6324224);                   // 2048x2304 f32
    float* qbuf = qkv;                                     // 2048x768 f32 (reuse)
    u16* gbuf  = (u16*)qkv;                                // 2048x3072 bf16 (reuse)
    float* cn  = (float*)(ws + 25198592);                  // 16x768
    float* kca = (float*)(ws + 25247744);                  // 16x768
    float* vca = (float*)(ws + 25296896);                  // 16x768

    // adaLN
    ada_gemm<<<1728, 256, 0, stream>>>(c, adaw, adab, mod);

    // ---- self-attention ----
    rms_mod<<<2048, 256, 0, stream>>>(x, n1w, mod, 0, hbuf);
    gemm_bt<0><<<dim3(18, 16), 256, 0, stream>>>(hbuf, saqkvw, 2048, 2304, 768,
                                                 qkv, nullptr, nullptr, nullptr, nullptr);
    saqk_rmsrope<<<12288, 256, 0, stream>>>(qkv, saqnw, saknw, cosT, sinT);
    sa_attn_mfma<<<dim3(32, 12), 256, 0, stream>>>(qkv, obuf);
    gemm_bt<2><<<dim3(6, 16), 256, 0, stream>>>(obuf, saprojw, 2048, 768, 768,
                                                out, nullptr, x, mod + 2 * 768, saprojb);

    // ---- cross-attention ----
    rms_mod<<<2048, 256, 0, stream>>>(out, n2w, mod, 3, hbuf);
    gemm_bt<0><<<dim3(6, 16), 256, 0, stream>>>(hbuf, caqw, 2048, 768, 768,
                                                qbuf, nullptr, nullptr, nullptr, nullptr);
    rms_plain<<<16, 256, 0, stream>>>(cond, cnw, cn);
    small_gemm_nt<<<6144, 256, 0, stream>>>(cn, cakw, cavw, kca, vca);
    cak_rms<<<48, 256, 0, stream>>>(kca, caknw);
    caq_rmsrope<<<6144, 256, 0, stream>>>(qbuf, caqnw, cosT, sinT);
    ca_attn<<<6144, 256, 0, stream>>>(qbuf, kca, vca, obuf);
    gemm_bt<2><<<dim3(6, 16), 256, 0, stream>>>(obuf, caprojw, 2048, 768, 768,
                                                out, nullptr, out, mod + 5 * 768, caprojb);

    // ---- SwiGLU MLP ----
    rms_mod<<<2048, 256, 0, stream>>>(out, n3w, mod, 6, hbuf);
    gemm_bt<3><<<dim3(24, 16), 256, 0, stream>>>(hbuf, w1, 2048, 3072, 768,
                                                 nullptr, gbuf, nullptr, nullptr, nullptr);
    gemm_bt<4><<<dim3(24, 16), 256, 0, stream>>>(hbuf, w3, 2048, 3072, 768,
                                                 nullptr, gbuf, nullptr, nullptr, nullptr);
    gemm_bt<2><<<dim3(6, 16), 256, 0, stream>>>(gbuf, w2, 2048, 768, 3072,
                                                out, nullptr, out, mod + 8 * 768, nullptr);
}

// Round 3
// 329.789 us; speedup vs baseline: 2.8051x; 1.4331x over previous
//
#include <hip/hip_runtime.h>

typedef unsigned short u16;
typedef unsigned int u32;
typedef __attribute__((ext_vector_type(8))) short s16x8;
typedef __attribute__((ext_vector_type(4))) float f32x4;
typedef __attribute__((ext_vector_type(4))) int i32x4;

// ---------- bf16 helpers (bit-level, RNE) ----------
static __device__ __forceinline__ float bf2f(u16 u) {
    return __uint_as_float(((u32)u) << 16);
}
static __device__ __forceinline__ u16 f2bf(float f) {
    u32 x = __float_as_uint(f);
    return (u16)((x + 0x7fffu + ((x >> 16) & 1u)) >> 16);
}
static __device__ __forceinline__ i32x4 pack8(float4 a, float4 b) {
    u32 p0 = (u32)f2bf(a.x) | ((u32)f2bf(a.y) << 16);
    u32 p1 = (u32)f2bf(a.z) | ((u32)f2bf(a.w) << 16);
    u32 p2 = (u32)f2bf(b.x) | ((u32)f2bf(b.y) << 16);
    u32 p3 = (u32)f2bf(b.z) | ((u32)f2bf(b.w) << 16);
    return (i32x4){(int)p0, (int)p1, (int)p2, (int)p3};
}
static __device__ __forceinline__ float wave_sum(float v) {
#pragma unroll
    for (int off = 32; off > 0; off >>= 1) v += __shfl_xor(v, off);
    return v;
}
// async global->LDS, 16B per lane; dest must be wave-uniform base (+lane*16 by HW)
static __device__ __forceinline__ void gload16(const u16* g, void* l) {
    __builtin_amdgcn_global_load_lds((const __attribute__((address_space(1))) void*)g,
                                     (__attribute__((address_space(3))) void*)l, 16, 0, 0);
}

// ---------- fp32 -> bf16 weight conversion (8 elems/thread) ----------
__global__ __launch_bounds__(256) void cvt_bf16(const float* __restrict__ src,
                                                u16* __restrict__ dst, int n8) {
    int i = blockIdx.x * 256 + threadIdx.x;
    if (i >= n8) return;
    float4 a = *(const float4*)(src + (size_t)i * 8);
    float4 b = *(const float4*)(src + (size_t)i * 8 + 4);
    *(i32x4*)(dst + (size_t)i * 8) = pack8(a, b);
}

// ---------- adaLN: mod = silu(c) @ ada_w.T + ada_b ----------
__global__ __launch_bounds__(256) void ada_gemm(const float* __restrict__ c,
                                                const float* __restrict__ adaw,
                                                const float* __restrict__ adab,
                                                float* __restrict__ mod) {
    int wid = blockIdx.x * 4 + (threadIdx.x >> 6);
    int lane = threadIdx.x & 63;
    float sum = 0.f;
#pragma unroll
    for (int i = 0; i < 12; ++i) {
        float cv = c[i * 64 + lane];
        cv = cv / (1.f + __expf(-cv));
        sum += cv * adaw[(size_t)wid * 768 + i * 64 + lane];
    }
    sum = wave_sum(sum);
    if (lane == 0) mod[wid] = sum + adab[wid];
}

// ---------- fused RMSNorm + modulate, writes bf16 ----------
__global__ __launch_bounds__(256) void rms_mod(const float* __restrict__ x,
                                               const float* __restrict__ w,
                                               const float* __restrict__ mod, int chunk,
                                               u16* __restrict__ out) {
    const int row = blockIdx.x;
    const int tid = threadIdx.x;
    const float* xr = x + (size_t)row * 768;
    float v0 = xr[tid], v1 = xr[256 + tid], v2 = xr[512 + tid];
    float ss = wave_sum(v0 * v0 + v1 * v1 + v2 * v2);
    __shared__ float red[4];
    if ((tid & 63) == 0) red[tid >> 6] = ss;
    __syncthreads();
    float rn = rsqrtf((red[0] + red[1] + red[2] + red[3]) * (1.f / 768.f) + 1e-6f);
    const float* sh = mod + chunk * 768;
    const float* sc = sh + 768;
    u16* orow = out + (size_t)row * 768;
    orow[tid]       = f2bf(v0 * rn * w[tid]       * (1.f + sc[tid])       + sh[tid]);
    orow[256 + tid] = f2bf(v1 * rn * w[256 + tid] * (1.f + sc[256 + tid]) + sh[256 + tid]);
    orow[512 + tid] = f2bf(v2 * rn * w[512 + tid] * (1.f + sc[512 + tid]) + sh[512 + tid]);
}

// ---------- plain RMSNorm (cond), fp32 out ----------
__global__ __launch_bounds__(256) void rms_plain(const float* __restrict__ x,
                                                 const float* __restrict__ w,
                                                 float* __restrict__ out) {
    const int row = blockIdx.x;
    const int tid = threadIdx.x;
    const float* xr = x + (size_t)row * 768;
    float v0 = xr[tid], v1 = xr[256 + tid], v2 = xr[512 + tid];
    float ss = wave_sum(v0 * v0 + v1 * v1 + v2 * v2);
    __shared__ float red[4];
    if ((tid & 63) == 0) red[tid >> 6] = ss;
    __syncthreads();
    float rn = rsqrtf((red[0] + red[1] + red[2] + red[3]) * (1.f / 768.f) + 1e-6f);
    float* orow = out + (size_t)row * 768;
    orow[tid]       = v0 * rn * w[tid];
    orow[256 + tid] = v1 * rn * w[256 + tid];
    orow[512 + tid] = v2 * rn * w[512 + tid];
}

// ---------- MFMA bf16 GEMM, global_load_lds + 2-phase double buffer ----------
// C[M,N] = A[M,K](bf16) @ Wb[N,K](bf16)^T.  128x128 tile, BK=64, 512 thr (8 waves 2x4).
// LDS linear dest; global source XOR-preswizzled (seg^=row&7); ds_read applies same XOR.
// EPI 0: f32 out. 1: bf16 out. 2: out = resid + gate[col]*(acc+bias[col]) f32.
// 3: bf16(silu(acc)). 4: outb[idx] = bf16(acc * bf2f(outb[idx])).
template <int EPI>
__global__ __launch_bounds__(512) void gemm_bt2(const u16* __restrict__ A,
                                                const u16* __restrict__ Wb,
                                                int M, int N, int K,
                                                float* outf, u16* outb,
                                                const float* resid,
                                                const float* __restrict__ gate,
                                                const float* __restrict__ bias) {
    __shared__ __align__(16) u16 As[2][128 * 64];
    __shared__ __align__(16) u16 Bs[2][128 * 64];
    const int tid = threadIdx.x;
    const int lane = tid & 63;
    const int w = tid >> 6;
    const int wr = w >> 2, wc = w & 3;  // 2x4 wave grid; per-wave 64x32 out
    const int row0 = blockIdx.y * 128, col0 = blockIdx.x * 128;

    // staging unit indices: issue0 unit=tid, issue1 unit=tid+512 (1024 units/tile)
    const int r0u = tid >> 3, s0u = (tid & 7) ^ (r0u & 7);
    const int r1u = (tid + 512) >> 3, s1u = (tid & 7) ^ (r1u & 7);
    const u16* a0 = A + (size_t)(row0 + r0u) * K + s0u * 8;
    const u16* a1 = A + (size_t)(row0 + r1u) * K + s1u * 8;
    const u16* b0 = Wb + (size_t)(col0 + r0u) * K + s0u * 8;
    const u16* b1 = Wb + (size_t)(col0 + r1u) * K + s1u * 8;

    f32x4 acc[4][2];
#pragma unroll
    for (int m = 0; m < 4; ++m)
#pragma unroll
        for (int n = 0; n < 2; ++n) acc[m][n] = (f32x4){0.f, 0.f, 0.f, 0.f};

    const int nt = K >> 6;
    int cur = 0;
    // prologue: stage tile 0 into buf 0
    {
        char* ad = (char*)As[0] + w * 1024;
        char* bd = (char*)Bs[0] + w * 1024;
        gload16(a0, ad);
        gload16(a1, ad + 8192);
        gload16(b0, bd);
        gload16(b1, bd + 8192);
    }
    for (int t = 0; t < nt; ++t) {
        __syncthreads();  // drains vmcnt: tile t staged; buf cur^1 free
        if (t + 1 < nt) {
            int k0 = (t + 1) << 6;
            char* ad = (char*)As[cur ^ 1] + w * 1024;
            char* bd = (char*)Bs[cur ^ 1] + w * 1024;
            gload16(a0 + k0, ad);
            gload16(a1 + k0, ad + 8192);
            gload16(b0 + k0, bd);
            gload16(b1 + k0, bd + 8192);
        }
#pragma unroll
        for (int kk = 0; kk < 2; ++kk) {
            s16x8 af[4], bfv[2];
#pragma unroll
            for (int m = 0; m < 4; ++m) {
                int ra = wr * 64 + m * 16 + (lane & 15);
                int u = (kk * 4 + (lane >> 4)) ^ (ra & 7);
                af[m] = *(const s16x8*)((const char*)As[cur] + ra * 128 + u * 16);
            }
#pragma unroll
            for (int n = 0; n < 2; ++n) {
                int cb = wc * 32 + n * 16 + (lane & 15);
                int u = (kk * 4 + (lane >> 4)) ^ (cb & 7);
                bfv[n] = *(const s16x8*)((const char*)Bs[cur] + cb * 128 + u * 16);
            }
#pragma unroll
            for (int m = 0; m < 4; ++m)
#pragma unroll
                for (int n = 0; n < 2; ++n)
                    acc[m][n] = __builtin_amdgcn_mfma_f32_16x16x32_bf16(af[m], bfv[n], acc[m][n], 0, 0, 0);
        }
        cur ^= 1;
    }
    // epilogue: C frag map col=lane&15, row=(lane>>4)*4+i (HW-verified)
#pragma unroll
    for (int m = 0; m < 4; ++m) {
#pragma unroll
        for (int n = 0; n < 2; ++n) {
#pragma unroll
            for (int i = 0; i < 4; ++i) {
                int r = row0 + wr * 64 + m * 16 + (lane >> 4) * 4 + i;
                int cc = col0 + wc * 32 + n * 16 + (lane & 15);
                size_t idx = (size_t)r * N + cc;
                float v = acc[m][n][i];
                if constexpr (EPI == 0) {
                    outf[idx] = v;
                } else if constexpr (EPI == 1) {
                    outb[idx] = f2bf(v);
                } else if constexpr (EPI == 2) {
                    float b = bias ? bias[cc] : 0.f;
                    outf[idx] = resid[idx] + gate[cc] * (v + b);
                } else if constexpr (EPI == 3) {
                    outb[idx] = f2bf(v / (1.f + __expf(-v)));
                } else if constexpr (EPI == 4) {
                    outb[idx] = f2bf(v * bf2f(outb[idx]));
                }
            }
        }
    }
}

// ---------- SA q/k: RMSNorm(head) + RoPE, in place on qkv bf16 ----------
__global__ __launch_bounds__(256) void saqk_rmsrope(u16* __restrict__ qkv,
                                                    const float* __restrict__ qnw,
                                                    const float* __restrict__ knw,
                                                    const float* __restrict__ cosT,
                                                    const float* __restrict__ sinT) {
    int wid = blockIdx.x * 4 + (threadIdx.x >> 6);  // 0..49151
    int lane = threadIdx.x & 63;
    int n = wid / 24;
    int rem = wid % 24;
    int which = rem / 12;  // 0=q 1=k
    int h = rem % 12;
    u16* p = qkv + (size_t)n * 2304 + which * 768 + h * 64 + lane;
    float v = bf2f(*p);
    float ss = wave_sum(v * v);
    const float* wv = which ? knw : qnw;
    float vn = v * rsqrtf(ss * (1.f / 64.f) + 1e-6f) * wv[lane];
    float part = __shfl_xor(vn, 32);
    float rot = (lane < 32) ? -part : part;
    *p = f2bf(vn * cosT[n * 64 + lane] + rot * sinT[n * 64 + lane]);
}

// ---------- CA q: RMSNorm + RoPE in place on qbuf f32 [2048][768] ----------
__global__ __launch_bounds__(256) void caq_rmsrope(float* __restrict__ qb,
                                                   const float* __restrict__ qnw,
                                                   const float* __restrict__ cosT,
                                                   const float* __restrict__ sinT) {
    int wid = blockIdx.x * 4 + (threadIdx.x >> 6);
    int lane = threadIdx.x & 63;
    int n = wid / 12, h = wid % 12;
    float* p = qb + (size_t)n * 768 + h * 64 + lane;
    float v = *p;
    float ss = wave_sum(v * v);
    float vn = v * rsqrtf(ss * (1.f / 64.f) + 1e-6f) * qnw[lane];
    float part = __shfl_xor(vn, 32);
    float rot = (lane < 32) ? -part : part;
    *p = vn * cosT[n * 64 + lane] + rot * sinT[n * 64 + lane];
}

// ---------- CA k: RMSNorm only, in place on kca [16][768] ----------
__global__ __launch_bounds__(256) void cak_rms(float* __restrict__ kca,
                                               const float* __restrict__ knw) {
    int wid = blockIdx.x * 4 + (threadIdx.x >> 6);  // 0..191
    int lane = threadIdx.x & 63;
    int n = wid / 12, h = wid % 12;
    float* p = kca + (size_t)n * 768 + h * 64 + lane;
    float v = *p;
    float ss = wave_sum(v * v);
    *p = v * rsqrtf(ss * (1.f / 64.f) + 1e-6f) * knw[lane];
}

// ---------- CA k/v small GEMM: [16,768] = cn[16,768] @ W[768,768]^T ----------
__global__ __launch_bounds__(256) void small_gemm_nt(const float* __restrict__ cn,
                                                     const float* __restrict__ cakw,
                                                     const float* __restrict__ cavw,
                                                     float* __restrict__ kca,
                                                     float* __restrict__ vca) {
    int wid = blockIdx.x * 4 + (threadIdx.x >> 6);  // 0..24575
    int lane = threadIdx.x & 63;
    int which = wid / 12288;
    int rem = wid % 12288;
    int rrow = rem / 768;
    int ocol = rem % 768;
    const float* Wm = which ? cavw : cakw;
    float sum = 0.f;
#pragma unroll
    for (int i = 0; i < 12; ++i)
        sum += cn[(size_t)rrow * 768 + i * 64 + lane] * Wm[(size_t)ocol * 768 + i * 64 + lane];
    sum = wave_sum(sum);
    if (lane == 0) (which ? vca : kca)[(size_t)rrow * 768 + ocol] = sum;
}

// ---------- SA flash attention, MFMA bf16 (qkv is bf16) ----------
__global__ __launch_bounds__(256) void sa_attn_mfma(const u16* __restrict__ qkv,
                                                    u16* __restrict__ obuf) {
    const int h = blockIdx.y;
    const int r0 = blockIdx.x * 64;
    const int tid = threadIdx.x;
    const int lane = tid & 63;
    const int w = tid >> 6;
    __shared__ __align__(16) u16 Ks[64 * 64];
    __shared__ __align__(16) u16 Vt[64 * 64];
    __shared__ __align__(16) u16 Ps[4][16 * 64];

    // Q fragments (A-operand), unscaled; 1/8 applied post-MFMA
    s16x8 qf[2];
    {
        const u16* qrow = qkv + (size_t)(r0 + w * 16 + (lane & 15)) * 2304 + h * 64 + ((lane >> 4) * 8);
        qf[0] = *(const s16x8*)qrow;
        qf[1] = *(const s16x8*)(qrow + 32);
    }
    f32x4 oacc[4];
#pragma unroll
    for (int n = 0; n < 4; ++n) oacc[n] = (f32x4){0.f, 0.f, 0.f, 0.f};
    float mrun[4] = {-1e30f, -1e30f, -1e30f, -1e30f};
    float lp[4] = {0.f, 0.f, 0.f, 0.f};

    const int key_s = tid >> 2;      // 4 threads per key row
    const int dseg = (tid & 3) * 16;

    for (int t = 0; t < 32; ++t) {
        __syncthreads();
        // stage K [64key][64d] swizzled, V^T [64d][64key] swizzled (bf16 direct)
        {
            const u16* kbase = qkv + (size_t)(t * 64 + key_s) * 2304 + 768 + h * 64 + dseg;
#pragma unroll
            for (int half = 0; half < 2; ++half) {
                int d0 = dseg + half * 8;
                int boff = key_s * 128 + ((d0 * 2) ^ ((key_s & 7) << 4));
                *(i32x4*)((char*)Ks + boff) = *(const i32x4*)(kbase + half * 8);
            }
            const u16* vbase = kbase + 768;
            s16x8 v0 = *(const s16x8*)vbase;
            s16x8 v1 = *(const s16x8*)(vbase + 8);
#pragma unroll
            for (int j = 0; j < 8; ++j) {
                int d = dseg + j;
                int boff = d * 128 + ((key_s * 2) ^ ((d & 7) << 4));
                *(u16*)((char*)Vt + boff) = (u16)v0[j];
                int d2 = d + 8;
                int boff2 = d2 * 128 + ((key_s * 2) ^ ((d2 & 7) << 4));
                *(u16*)((char*)Vt + boff2) = (u16)v1[j];
            }
        }
        __syncthreads();
        // QK^T
        f32x4 sacc[4];
#pragma unroll
        for (int n = 0; n < 4; ++n) sacc[n] = (f32x4){0.f, 0.f, 0.f, 0.f};
#pragma unroll
        for (int kk = 0; kk < 2; ++kk) {
#pragma unroll
            for (int n = 0; n < 4; ++n) {
                int key = n * 16 + (lane & 15);
                int d = kk * 32 + (lane >> 4) * 8;
                int boff = key * 128 + ((d * 2) ^ ((key & 7) << 4));
                s16x8 kf = *(const s16x8*)((const char*)Ks + boff);
                sacc[n] = __builtin_amdgcn_mfma_f32_16x16x32_bf16(qf[kk], kf, sacc[n], 0, 0, 0);
            }
        }
#pragma unroll
        for (int n = 0; n < 4; ++n)
#pragma unroll
            for (int i = 0; i < 4; ++i) sacc[n][i] *= 0.125f;  // qk scale
        // online softmax
        float tmax[4];
#pragma unroll
        for (int i = 0; i < 4; ++i)
            tmax[i] = fmaxf(fmaxf(sacc[0][i], sacc[1][i]), fmaxf(sacc[2][i], sacc[3][i]));
#pragma unroll
        for (int off = 1; off < 16; off <<= 1) {
#pragma unroll
            for (int i = 0; i < 4; ++i) tmax[i] = fmaxf(tmax[i], __shfl_xor(tmax[i], off));
        }
        float corr[4];
#pragma unroll
        for (int i = 0; i < 4; ++i) {
            float mn = fmaxf(mrun[i], tmax[i]);
            corr[i] = __expf(mrun[i] - mn);
            mrun[i] = mn;
            lp[i] *= corr[i];
        }
#pragma unroll
        for (int n = 0; n < 4; ++n) {
#pragma unroll
            for (int i = 0; i < 4; ++i) oacc[n][i] *= corr[i];
        }
#pragma unroll
        for (int n = 0; n < 4; ++n) {
#pragma unroll
            for (int i = 0; i < 4; ++i) {
                float p = __expf(sacc[n][i] - mrun[i]);
                lp[i] += p;
                int row = (lane >> 4) * 4 + i;
                int key = n * 16 + (lane & 15);
                int boff = row * 128 + ((key * 2) ^ ((row & 7) << 4));
                *(u16*)((char*)Ps[w] + boff) = f2bf(p);
            }
        }
        // PV
#pragma unroll
        for (int ks = 0; ks < 2; ++ks) {
            int prow = lane & 15;
            int koff = ks * 32 + (lane >> 4) * 8;
            int pboff = prow * 128 + ((koff * 2) ^ ((prow & 7) << 4));
            s16x8 pf = *(const s16x8*)((const char*)Ps[w] + pboff);
#pragma unroll
            for (int n = 0; n < 4; ++n) {
                int d = n * 16 + (lane & 15);
                int vboff = d * 128 + ((koff * 2) ^ ((d & 7) << 4));
                s16x8 vf = *(const s16x8*)((const char*)Vt + vboff);
                oacc[n] = __builtin_amdgcn_mfma_f32_16x16x32_bf16(pf, vf, oacc[n], 0, 0, 0);
            }
        }
    }
#pragma unroll
    for (int off = 1; off < 16; off <<= 1) {
#pragma unroll
        for (int i = 0; i < 4; ++i) lp[i] += __shfl_xor(lp[i], off);
    }
#pragma unroll
    for (int i = 0; i < 4; ++i) lp[i] = 1.f / lp[i];
#pragma unroll
    for (int n = 0; n < 4; ++n) {
#pragma unroll
        for (int i = 0; i < 4; ++i) {
            int r = r0 + w * 16 + (lane >> 4) * 4 + i;
            int d = n * 16 + (lane & 15);
            obuf[(size_t)r * 768 + h * 64 + d] = f2bf(oacc[n][i] * lp[i]);
        }
    }
}

// ---------- CA attention ----------
__global__ __launch_bounds__(256) void ca_attn(const float* __restrict__ qb,
                                               const float* __restrict__ kca,
                                               const float* __restrict__ vca,
                                               u16* __restrict__ obuf) {
    int wid = blockIdx.x * 4 + (threadIdx.x >> 6);
    int lane = threadIdx.x & 63;
    int n = wid / 12, h = wid % 12;
    float qd = qb[(size_t)n * 768 + h * 64 + lane] * 0.125f;
    float s[16];
#pragma unroll
    for (int j = 0; j < 16; ++j) {
        float part = qd * kca[(size_t)j * 768 + h * 64 + lane];
        s[j] = wave_sum(part);
    }
    float mm = s[0];
#pragma unroll
    for (int j = 1; j < 16; ++j) mm = fmaxf(mm, s[j]);
    float l = 0.f;
#pragma unroll
    for (int j = 0; j < 16; ++j) { s[j] = __expf(s[j] - mm); l += s[j]; }
    float od = 0.f;
#pragma unroll
    for (int j = 0; j < 16; ++j) od += s[j] * vca[(size_t)j * 768 + h * 64 + lane];
    obuf[(size_t)n * 768 + h * 64 + lane] = f2bf(od / l);
}

// =======================================================================
extern "C" void kernel_launch(void* const* d_in, const int* in_sizes, int n_in,
                              void* d_out, int out_size, void* d_ws, size_t ws_size,
                              hipStream_t stream) {
    const float* x     = (const float*)d_in[0];
    const float* c     = (const float*)d_in[1];
    const float* cond  = (const float*)d_in[2];
    const float* cosT  = (const float*)d_in[3];
    const float* sinT  = (const float*)d_in[4];
    const float* n1w   = (const float*)d_in[5];
    const float* n2w   = (const float*)d_in[6];
    const float* n3w   = (const float*)d_in[7];
    const float* cnw   = (const float*)d_in[8];
    const float* saqkvw  = (const float*)d_in[9];
    const float* saprojw = (const float*)d_in[10];
    const float* saprojb = (const float*)d_in[11];
    const float* saqnw   = (const float*)d_in[12];
    const float* saknw   = (const float*)d_in[13];
    const float* caqw    = (const float*)d_in[14];
    const float* cakw    = (const float*)d_in[15];
    const float* cavw    = (const float*)d_in[16];
    const float* caprojw = (const float*)d_in[17];
    const float* caprojb = (const float*)d_in[18];
    const float* caqnw   = (const float*)d_in[19];
    const float* caknw   = (const float*)d_in[20];
    const float* w1      = (const float*)d_in[21];
    const float* w2      = (const float*)d_in[22];
    const float* w3      = (const float*)d_in[23];
    const float* adaw    = (const float*)d_in[24];
    const float* adab    = (const float*)d_in[25];
    float* out = (float*)d_out;
    char* ws = (char*)d_ws;

    // ws layout (bytes):
    float* mod  = (float*)ws;                      // 0      : 27,648
    u16* hbuf   = (u16*)(ws + 32768);              // 32,768 : 3,145,728 (2048x768 bf16)
    u16* obuf   = (u16*)(ws + 3178496);            //         3,145,728
    char* R1    = ws + 6324224;                    // 12,582,912 shared region
    u16* qkvb   = (u16*)R1;                        //   qkv bf16 [2048][2304]
    float* qbuf = (float*)R1;                      //   CA q f32 [2048][768]
    u16* gbuf   = (u16*)R1;                        //   MLP gate bf16 [2048][3072]
    float* cn   = (float*)(ws + 18907136);         // 49,152
    float* kca  = (float*)(ws + 18956288);         // 49,152
    float* vca  = (float*)(ws + 19005440);         // 49,152
    u16* wbuf   = (u16*)(ws + 19054592);           // 4,718,592 rotating bf16 weights
    // total 23,773,184 B

    ada_gemm<<<1728, 256, 0, stream>>>(c, adaw, adab, mod);

    // ---- self-attention ----
    rms_mod<<<2048, 256, 0, stream>>>(x, n1w, mod, 0, hbuf);
    cvt_bf16<<<864, 256, 0, stream>>>(saqkvw, wbuf, 221184);
    gemm_bt2<1><<<dim3(18, 16), 512, 0, stream>>>(hbuf, wbuf, 2048, 2304, 768,
                                                  nullptr, qkvb, nullptr, nullptr, nullptr);
    saqk_rmsrope<<<12288, 256, 0, stream>>>(qkvb, saqnw, saknw, cosT, sinT);
    sa_attn_mfma<<<dim3(32, 12), 256, 0, stream>>>(qkvb, obuf);
    cvt_bf16<<<288, 256, 0, stream>>>(saprojw, wbuf, 73728);
    gemm_bt2<2><<<dim3(6, 16), 512, 0, stream>>>(obuf, wbuf, 2048, 768, 768,
                                                 out, nullptr, x, mod + 2 * 768, saprojb);

    // ---- cross-attention ----
    rms_mod<<<2048, 256, 0, stream>>>(out, n2w, mod, 3, hbuf);
    cvt_bf16<<<288, 256, 0, stream>>>(caqw, wbuf, 73728);
    gemm_bt2<0><<<dim3(6, 16), 512, 0, stream>>>(hbuf, wbuf, 2048, 768, 768,
                                                 qbuf, nullptr, nullptr, nullptr, nullptr);
    rms_plain<<<16, 256, 0, stream>>>(cond, cnw, cn);
    small_gemm_nt<<<6144, 256, 0, stream>>>(cn, cakw, cavw, kca, vca);
    cak_rms<<<48, 256, 0, stream>>>(kca, caknw);
    caq_rmsrope<<<6144, 256, 0, stream>>>(qbuf, caqnw, cosT, sinT);
    ca_attn<<<6144, 256, 0, stream>>>(qbuf, kca, vca, obuf);
    cvt_bf16<<<288, 256, 0, stream>>>(caprojw, wbuf, 73728);
    gemm_bt2<2><<<dim3(6, 16), 512, 0, stream>>>(obuf, wbuf, 2048, 768, 768,
                                                 out, nullptr, out, mod + 5 * 768, caprojb);

    // ---- SwiGLU MLP ----
    rms_mod<<<2048, 256, 0, stream>>>(out, n3w, mod, 6, hbuf);
    cvt_bf16<<<1152, 256, 0, stream>>>(w1, wbuf, 294912);
    gemm_bt2<3><<<dim3(24, 16), 512, 0, stream>>>(hbuf, wbuf, 2048, 3072, 768,
                                                  nullptr, gbuf, nullptr, nullptr, nullptr);
    cvt_bf16<<<1152, 256, 0, stream>>>(w3, wbuf, 294912);
    gemm_bt2<4><<<dim3(24, 16), 512, 0, stream>>>(hbuf, wbuf, 2048, 3072, 768,
                                                  nullptr, gbuf, nullptr, nullptr, nullptr);
    cvt_bf16<<<1152, 256, 0, stream>>>(w2, wbuf, 294912);
    gemm_bt2<2><<<dim3(6, 16), 512, 0, stream>>>(gbuf, wbuf, 2048, 768, 3072,
                                                 out, nullptr, out, mod + 8 * 768, nullptr);
}

// Round 5
// 329.220 us; speedup vs baseline: 2.8099x; 1.0017x over previous
//
#include <hip/hip_runtime.h>

typedef unsigned short u16;
typedef unsigned int u32;
typedef __attribute__((ext_vector_type(8))) short s16x8;
typedef __attribute__((ext_vector_type(4))) float f32x4;
typedef __attribute__((ext_vector_type(4))) int i32x4;

// ---------- bf16 helpers (bit-level, RNE) ----------
static __device__ __forceinline__ float bf2f(u16 u) {
    return __uint_as_float(((u32)u) << 16);
}
static __device__ __forceinline__ u16 f2bf(float f) {
    u32 x = __float_as_uint(f);
    return (u16)((x + 0x7fffu + ((x >> 16) & 1u)) >> 16);
}
static __device__ __forceinline__ i32x4 pack8(float4 a, float4 b) {
    u32 p0 = (u32)f2bf(a.x) | ((u32)f2bf(a.y) << 16);
    u32 p1 = (u32)f2bf(a.z) | ((u32)f2bf(a.w) << 16);
    u32 p2 = (u32)f2bf(b.x) | ((u32)f2bf(b.y) << 16);
    u32 p3 = (u32)f2bf(b.z) | ((u32)f2bf(b.w) << 16);
    return (i32x4){(int)p0, (int)p1, (int)p2, (int)p3};
}
static __device__ __forceinline__ float wave_sum(float v) {
#pragma unroll
    for (int off = 32; off > 0; off >>= 1) v += __shfl_xor(v, off);
    return v;
}
// async global->LDS, 16B per lane; dest is wave-uniform base (+lane*16 by HW)
static __device__ __forceinline__ void gload16(const u16* g, void* l) {
    __builtin_amdgcn_global_load_lds((const __attribute__((address_space(1))) void*)g,
                                     (__attribute__((address_space(3))) void*)l, 16, 0, 0);
}

// ---------- fp32 -> bf16 weight conversion (8 elems/thread) ----------
__global__ __launch_bounds__(256) void cvt_bf16(const float* __restrict__ src,
                                                u16* __restrict__ dst, int n8) {
    int i = blockIdx.x * 256 + threadIdx.x;
    if (i >= n8) return;
    float4 a = *(const float4*)(src + (size_t)i * 8);
    float4 b = *(const float4*)(src + (size_t)i * 8 + 4);
    *(i32x4*)(dst + (size_t)i * 8) = pack8(a, b);
}

// ---------- adaLN: mod = silu(c) @ ada_w.T + ada_b ----------
__global__ __launch_bounds__(256) void ada_gemm(const float* __restrict__ c,
                                                const float* __restrict__ adaw,
                                                const float* __restrict__ adab,
                                                float* __restrict__ mod) {
    int wid = blockIdx.x * 4 + (threadIdx.x >> 6);
    int lane = threadIdx.x & 63;
    float sum = 0.f;
#pragma unroll
    for (int i = 0; i < 12; ++i) {
        float cv = c[i * 64 + lane];
        cv = cv / (1.f + __expf(-cv));
        sum += cv * adaw[(size_t)wid * 768 + i * 64 + lane];
    }
    sum = wave_sum(sum);
    if (lane == 0) mod[wid] = sum + adab[wid];
}

// ---------- fused RMSNorm + modulate, writes bf16 ----------
__global__ __launch_bounds__(256) void rms_mod(const float* __restrict__ x,
                                               const float* __restrict__ w,
                                               const float* __restrict__ mod, int chunk,
                                               u16* __restrict__ out) {
    const int row = blockIdx.x;
    const int tid = threadIdx.x;
    const float* xr = x + (size_t)row * 768;
    float v0 = xr[tid], v1 = xr[256 + tid], v2 = xr[512 + tid];
    float ss = wave_sum(v0 * v0 + v1 * v1 + v2 * v2);
    __shared__ float red[4];
    if ((tid & 63) == 0) red[tid >> 6] = ss;
    __syncthreads();
    float rn = rsqrtf((red[0] + red[1] + red[2] + red[3]) * (1.f / 768.f) + 1e-6f);
    const float* sh = mod + chunk * 768;
    const float* sc = sh + 768;
    u16* orow = out + (size_t)row * 768;
    orow[tid]       = f2bf(v0 * rn * w[tid]       * (1.f + sc[tid])       + sh[tid]);
    orow[256 + tid] = f2bf(v1 * rn * w[256 + tid] * (1.f + sc[256 + tid]) + sh[256 + tid]);
    orow[512 + tid] = f2bf(v2 * rn * w[512 + tid] * (1.f + sc[512 + tid]) + sh[512 + tid]);
}

// ---------- plain RMSNorm (cond), fp32 out ----------
__global__ __launch_bounds__(256) void rms_plain(const float* __restrict__ x,
                                                 const float* __restrict__ w,
                                                 float* __restrict__ out) {
    const int row = blockIdx.x;
    const int tid = threadIdx.x;
    const float* xr = x + (size_t)row * 768;
    float v0 = xr[tid], v1 = xr[256 + tid], v2 = xr[512 + tid];
    float ss = wave_sum(v0 * v0 + v1 * v1 + v2 * v2);
    __shared__ float red[4];
    if ((tid & 63) == 0) red[tid >> 6] = ss;
    __syncthreads();
    float rn = rsqrtf((red[0] + red[1] + red[2] + red[3]) * (1.f / 768.f) + 1e-6f);
    float* orow = out + (size_t)row * 768;
    orow[tid]       = v0 * rn * w[tid];
    orow[256 + tid] = v1 * rn * w[256 + tid];
    orow[512 + tid] = v2 * rn * w[512 + tid];
}

// ---------- MFMA bf16 GEMM, global_load_lds + 2-phase double buffer ----------
template <int EPI>
__global__ __launch_bounds__(512) void gemm_bt2(const u16* __restrict__ A,
                                                const u16* __restrict__ Wb,
                                                int M, int N, int K,
                                                float* outf, u16* outb,
                                                const float* resid,
                                                const float* __restrict__ gate,
                                                const float* __restrict__ bias) {
    __shared__ __align__(16) u16 As[2][128 * 64];
    __shared__ __align__(16) u16 Bs[2][128 * 64];
    const int tid = threadIdx.x;
    const int lane = tid & 63;
    const int w = tid >> 6;
    const int wr = w >> 2, wc = w & 3;  // 2x4 wave grid; per-wave 64x32 out
    const int row0 = blockIdx.y * 128, col0 = blockIdx.x * 128;

    const int r0u = tid >> 3, s0u = (tid & 7) ^ (r0u & 7);
    const int r1u = (tid + 512) >> 3, s1u = (tid & 7) ^ (r1u & 7);
    const u16* a0 = A + (size_t)(row0 + r0u) * K + s0u * 8;
    const u16* a1 = A + (size_t)(row0 + r1u) * K + s1u * 8;
    const u16* b0 = Wb + (size_t)(col0 + r0u) * K + s0u * 8;
    const u16* b1 = Wb + (size_t)(col0 + r1u) * K + s1u * 8;

    f32x4 acc[4][2];
#pragma unroll
    for (int m = 0; m < 4; ++m)
#pragma unroll
        for (int n = 0; n < 2; ++n) acc[m][n] = (f32x4){0.f, 0.f, 0.f, 0.f};

    const int nt = K >> 6;
    int cur = 0;
    {
        char* ad = (char*)As[0] + w * 1024;
        char* bd = (char*)Bs[0] + w * 1024;
        gload16(a0, ad);
        gload16(a1, ad + 8192);
        gload16(b0, bd);
        gload16(b1, bd + 8192);
    }
    for (int t = 0; t < nt; ++t) {
        __syncthreads();
        if (t + 1 < nt) {
            int k0 = (t + 1) << 6;
            char* ad = (char*)As[cur ^ 1] + w * 1024;
            char* bd = (char*)Bs[cur ^ 1] + w * 1024;
            gload16(a0 + k0, ad);
            gload16(a1 + k0, ad + 8192);
            gload16(b0 + k0, bd);
            gload16(b1 + k0, bd + 8192);
        }
#pragma unroll
        for (int kk = 0; kk < 2; ++kk) {
            s16x8 af[4], bfv[2];
#pragma unroll
            for (int m = 0; m < 4; ++m) {
                int ra = wr * 64 + m * 16 + (lane & 15);
                int u = (kk * 4 + (lane >> 4)) ^ (ra & 7);
                af[m] = *(const s16x8*)((const char*)As[cur] + ra * 128 + u * 16);
            }
#pragma unroll
            for (int n = 0; n < 2; ++n) {
                int cb = wc * 32 + n * 16 + (lane & 15);
                int u = (kk * 4 + (lane >> 4)) ^ (cb & 7);
                bfv[n] = *(const s16x8*)((const char*)Bs[cur] + cb * 128 + u * 16);
            }
#pragma unroll
            for (int m = 0; m < 4; ++m)
#pragma unroll
                for (int n = 0; n < 2; ++n)
                    acc[m][n] = __builtin_amdgcn_mfma_f32_16x16x32_bf16(af[m], bfv[n], acc[m][n], 0, 0, 0);
        }
        cur ^= 1;
    }
#pragma unroll
    for (int m = 0; m < 4; ++m) {
#pragma unroll
        for (int n = 0; n < 2; ++n) {
#pragma unroll
            for (int i = 0; i < 4; ++i) {
                int r = row0 + wr * 64 + m * 16 + (lane >> 4) * 4 + i;
                int cc = col0 + wc * 32 + n * 16 + (lane & 15);
                size_t idx = (size_t)r * N + cc;
                float v = acc[m][n][i];
                if constexpr (EPI == 0) {
                    outf[idx] = v;
                } else if constexpr (EPI == 1) {
                    outb[idx] = f2bf(v);
                } else if constexpr (EPI == 2) {
                    float b = bias ? bias[cc] : 0.f;
                    outf[idx] = resid[idx] + gate[cc] * (v + b);
                } else if constexpr (EPI == 3) {
                    outb[idx] = f2bf(v / (1.f + __expf(-v)));
                } else if constexpr (EPI == 4) {
                    outb[idx] = f2bf(v * bf2f(outb[idx]));
                }
            }
        }
    }
}

// ---------- SA q/k: RMSNorm(head) + RoPE, in place on qkv bf16 ----------
__global__ __launch_bounds__(256) void saqk_rmsrope(u16* __restrict__ qkv,
                                                    const float* __restrict__ qnw,
                                                    const float* __restrict__ knw,
                                                    const float* __restrict__ cosT,
                                                    const float* __restrict__ sinT) {
    int wid = blockIdx.x * 4 + (threadIdx.x >> 6);  // 0..49151
    int lane = threadIdx.x & 63;
    int n = wid / 24;
    int rem = wid % 24;
    int which = rem / 12;  // 0=q 1=k
    int h = rem % 12;
    u16* p = qkv + (size_t)n * 2304 + which * 768 + h * 64 + lane;
    float v = bf2f(*p);
    float ss = wave_sum(v * v);
    const float* wv = which ? knw : qnw;
    float vn = v * rsqrtf(ss * (1.f / 64.f) + 1e-6f) * wv[lane];
    float part = __shfl_xor(vn, 32);
    float rot = (lane < 32) ? -part : part;
    *p = f2bf(vn * cosT[n * 64 + lane] + rot * sinT[n * 64 + lane]);
}

// ---------- V transpose: qkv V part [2048][12*64] -> vT [12][64][2048] ----------
__global__ __launch_bounds__(256) void v_transpose(const u16* __restrict__ qkv,
                                                   u16* __restrict__ vT) {
    const int kt = blockIdx.x, h = blockIdx.y;
    const int tid = threadIdx.x;
    __shared__ __align__(16) u16 tt[64][72];  // +8 pad breaks bank conflicts
    {
        int key = tid >> 2, qq = tid & 3;
        const u16* src = qkv + (size_t)(kt * 64 + key) * 2304 + 1536 + h * 64 + qq * 16;
        *(i32x4*)&tt[key][qq * 16]     = *(const i32x4*)src;
        *(i32x4*)&tt[key][qq * 16 + 8] = *(const i32x4*)(src + 8);
    }
    __syncthreads();
    {
        int d = tid >> 2, kq = tid & 3;
        s16x8 o0, o1;
#pragma unroll
        for (int e = 0; e < 8; ++e) o0[e] = (short)tt[kq * 16 + e][d];
#pragma unroll
        for (int e = 0; e < 8; ++e) o1[e] = (short)tt[kq * 16 + 8 + e][d];
        u16* dst = vT + (size_t)h * 131072 + (size_t)d * 2048 + kt * 64 + kq * 16;
        *(s16x8*)dst = o0;
        *(s16x8*)(dst + 8) = o1;
    }
}

// ---------- SA flash attention, MFMA bf16, gload_lds-staged K and V^T ----------
// Block: head h, 64 q rows, 4 waves x 16 q rows. 32 tiles of 64 keys, double-buffered,
// one barrier per tile. K tile [64key][64d], V^T tile [64d][64key]; both staged via
// global_load_lds with inverse-XOR-preswizzled source (linear LDS dest), read with
// the matching XOR — identical pattern to gemm_bt2 (proven).
__global__ __launch_bounds__(256) void sa_attn_mfma(const u16* __restrict__ qkv,
                                                    const u16* __restrict__ vT,
                                                    u16* __restrict__ obuf) {
    const int h = blockIdx.y;
    const int r0 = blockIdx.x * 64;
    const int tid = threadIdx.x;
    const int lane = tid & 63;
    const int w = tid >> 6;
    __shared__ __align__(16) u16 Ks[2][64 * 64];
    __shared__ __align__(16) u16 Vs[2][64 * 64];
    __shared__ __align__(16) u16 Ps[4][16 * 64];

    // Q fragments (A-operand), unscaled; 1/8 applied post-MFMA
    s16x8 qf[2];
    {
        const u16* qrow = qkv + (size_t)(r0 + w * 16 + (lane & 15)) * 2304 + h * 64 + ((lane >> 4) * 8);
        qf[0] = *(const s16x8*)qrow;
        qf[1] = *(const s16x8*)(qrow + 32);
    }
    f32x4 oacc[4];
#pragma unroll
    for (int n = 0; n < 4; ++n) oacc[n] = (f32x4){0.f, 0.f, 0.f, 0.f};
    float mrun[4] = {-1e30f, -1e30f, -1e30f, -1e30f};
    float lp[4] = {0.f, 0.f, 0.f, 0.f};

    // staging source pointers; wave w stages 16B-units (w*2+j)*64+lane of each tile
    const u16* ksrc[2];
    const u16* vsrc[2];
#pragma unroll
    for (int j = 0; j < 2; ++j) {
        int u = (w * 2 + j) * 64 + lane;
        int row = u >> 3, seg = (u & 7) ^ (row & 7);
        ksrc[j] = qkv + (size_t)row * 2304 + 768 + h * 64 + seg * 8;          // K[key=row]
        vsrc[j] = vT + (size_t)h * 131072 + (size_t)row * 2048 + seg * 8;     // V^T[d=row]
    }

#define SA_STAGE(buf, t_)                                          \
    {                                                              \
        char* kd = (char*)Ks[buf] + w * 2048;                      \
        char* vd = (char*)Vs[buf] + w * 2048;                      \
        gload16(ksrc[0] + (size_t)(t_) * 147456, kd);              \
        gload16(ksrc[1] + (size_t)(t_) * 147456, kd + 1024);       \
        gload16(vsrc[0] + (t_) * 64, vd);                          \
        gload16(vsrc[1] + (t_) * 64, vd + 1024);                   \
    }

    SA_STAGE(0, 0)
    int cur = 0;
    for (int t = 0; t < 32; ++t) {
        __syncthreads();  // drains vmcnt: tile t staged; buf cur^1 free
        if (t + 1 < 32) SA_STAGE(cur ^ 1, t + 1)

        // ---- QK^T: S[16 rows][64 keys] per wave ----
        f32x4 sacc[4];
#pragma unroll
        for (int n = 0; n < 4; ++n) sacc[n] = (f32x4){0.f, 0.f, 0.f, 0.f};
#pragma unroll
        for (int kk = 0; kk < 2; ++kk) {
#pragma unroll
            for (int n = 0; n < 4; ++n) {
                int key = n * 16 + (lane & 15);
                int d = kk * 32 + (lane >> 4) * 8;
                int boff = key * 128 + ((d * 2) ^ ((key & 7) << 4));
                s16x8 kf = *(const s16x8*)((const char*)Ks[cur] + boff);
                sacc[n] = __builtin_amdgcn_mfma_f32_16x16x32_bf16(qf[kk], kf, sacc[n], 0, 0, 0);
            }
        }
#pragma unroll
        for (int n = 0; n < 4; ++n)
#pragma unroll
            for (int i = 0; i < 4; ++i) sacc[n][i] *= 0.125f;  // qk scale
        // ---- online softmax (rows=(lane>>4)*4+i, keys across 16-lane group) ----
        float tmax[4];
#pragma unroll
        for (int i = 0; i < 4; ++i)
            tmax[i] = fmaxf(fmaxf(sacc[0][i], sacc[1][i]), fmaxf(sacc[2][i], sacc[3][i]));
#pragma unroll
        for (int off = 1; off < 16; off <<= 1) {
#pragma unroll
            for (int i = 0; i < 4; ++i) tmax[i] = fmaxf(tmax[i], __shfl_xor(tmax[i], off));
        }
        float corr[4];
#pragma unroll
        for (int i = 0; i < 4; ++i) {
            float mn = fmaxf(mrun[i], tmax[i]);
            corr[i] = __expf(mrun[i] - mn);
            mrun[i] = mn;
            lp[i] *= corr[i];
        }
#pragma unroll
        for (int n = 0; n < 4; ++n) {
#pragma unroll
            for (int i = 0; i < 4; ++i) oacc[n][i] *= corr[i];
        }
#pragma unroll
        for (int n = 0; n < 4; ++n) {
#pragma unroll
            for (int i = 0; i < 4; ++i) {
                float p = __expf(sacc[n][i] - mrun[i]);
                lp[i] += p;
                int row = (lane >> 4) * 4 + i;
                int key = n * 16 + (lane & 15);
                int boff = row * 128 + ((key * 2) ^ ((row & 7) << 4));
                *(u16*)((char*)Ps[w] + boff) = f2bf(p);
            }
        }
        // ---- PV: O[16q][64d] += P[16q][64k] @ V[64k][64d]  (B-frag from V^T tile) ----
#pragma unroll
        for (int kk = 0; kk < 2; ++kk) {
            int koff = kk * 32 + (lane >> 4) * 8;
            int prow = lane & 15;
            int pboff = prow * 128 + ((koff * 2) ^ ((prow & 7) << 4));
            s16x8 pf = *(const s16x8*)((const char*)Ps[w] + pboff);
#pragma unroll
            for (int n = 0; n < 4; ++n) {
                int d = n * 16 + (lane & 15);
                int vboff = d * 128 + ((koff * 2) ^ ((d & 7) << 4));
                s16x8 vf = *(const s16x8*)((const char*)Vs[cur] + vboff);
                oacc[n] = __builtin_amdgcn_mfma_f32_16x16x32_bf16(pf, vf, oacc[n], 0, 0, 0);
            }
        }
        cur ^= 1;
    }
#undef SA_STAGE
#pragma unroll
    for (int off = 1; off < 16; off <<= 1) {
#pragma unroll
        for (int i = 0; i < 4; ++i) lp[i] += __shfl_xor(lp[i], off);
    }
#pragma unroll
    for (int i = 0; i < 4; ++i) lp[i] = 1.f / lp[i];
#pragma unroll
    for (int n = 0; n < 4; ++n) {
#pragma unroll
        for (int i = 0; i < 4; ++i) {
            int r = r0 + w * 16 + (lane >> 4) * 4 + i;
            int d = n * 16 + (lane & 15);
            obuf[(size_t)r * 768 + h * 64 + d] = f2bf(oacc[n][i] * lp[i]);
        }
    }
}

// ---------- CA attention ----------
__global__ __launch_bounds__(256) void ca_attn(const float* __restrict__ qb,
                                               const float* __restrict__ kca,
                                               const float* __restrict__ vca,
                                               u16* __restrict__ obuf) {
    int wid = blockIdx.x * 4 + (threadIdx.x >> 6);
    int lane = threadIdx.x & 63;
    int n = wid / 12, h = wid % 12;
    float qd = qb[(size_t)n * 768 + h * 64 + lane] * 0.125f;
    float s[16];
#pragma unroll
    for (int j = 0; j < 16; ++j) {
        float part = qd * kca[(size_t)j * 768 + h * 64 + lane];
        s[j] = wave_sum(part);
    }
    float mm = s[0];
#pragma unroll
    for (int j = 1; j < 16; ++j) mm = fmaxf(mm, s[j]);
    float l = 0.f;
#pragma unroll
    for (int j = 0; j < 16; ++j) { s[j] = __expf(s[j] - mm); l += s[j]; }
    float od = 0.f;
#pragma unroll
    for (int j = 0; j < 16; ++j) od += s[j] * vca[(size_t)j * 768 + h * 64 + lane];
    obuf[(size_t)n * 768 + h * 64 + lane] = f2bf(od / l);
}

// ---------- CA q: RMSNorm + RoPE in place on qbuf f32 [2048][768] ----------
__global__ __launch_bounds__(256) void caq_rmsrope(float* __restrict__ qb,
                                                   const float* __restrict__ qnw,
                                                   const float* __restrict__ cosT,
                                                   const float* __restrict__ sinT) {
    int wid = blockIdx.x * 4 + (threadIdx.x >> 6);
    int lane = threadIdx.x & 63;
    int n = wid / 12, h = wid % 12;
    float* p = qb + (size_t)n * 768 + h * 64 + lane;
    float v = *p;
    float ss = wave_sum(v * v);
    float vn = v * rsqrtf(ss * (1.f / 64.f) + 1e-6f) * qnw[lane];
    float part = __shfl_xor(vn, 32);
    float rot = (lane < 32) ? -part : part;
    *p = vn * cosT[n * 64 + lane] + rot * sinT[n * 64 + lane];
}

// ---------- CA k: RMSNorm only, in place on kca [16][768] ----------
__global__ __launch_bounds__(256) void cak_rms(float* __restrict__ kca,
                                               const float* __restrict__ knw) {
    int wid = blockIdx.x * 4 + (threadIdx.x >> 6);  // 0..191
    int lane = threadIdx.x & 63;
    int n = wid / 12, h = wid % 12;
    float* p = kca + (size_t)n * 768 + h * 64 + lane;
    float v = *p;
    float ss = wave_sum(v * v);
    *p = v * rsqrtf(ss * (1.f / 64.f) + 1e-6f) * knw[lane];
}

// ---------- CA k/v small GEMM: [16,768] = cn[16,768] @ W[768,768]^T ----------
__global__ __launch_bounds__(256) void small_gemm_nt(const float* __restrict__ cn,
                                                     const float* __restrict__ cakw,
                                                     const float* __restrict__ cavw,
                                                     float* __restrict__ kca,
                                                     float* __restrict__ vca) {
    int wid = blockIdx.x * 4 + (threadIdx.x >> 6);  // 0..24575
    int lane = threadIdx.x & 63;
    int which = wid / 12288;
    int rem = wid % 12288;
    int rrow = rem / 768;
    int ocol = rem % 768;
    const float* Wm = which ? cavw : cakw;
    float sum = 0.f;
#pragma unroll
    for (int i = 0; i < 12; ++i)
        sum += cn[(size_t)rrow * 768 + i * 64 + lane] * Wm[(size_t)ocol * 768 + i * 64 + lane];
    sum = wave_sum(sum);
    if (lane == 0) (which ? vca : kca)[(size_t)rrow * 768 + ocol] = sum;
}

// =======================================================================
extern "C" void kernel_launch(void* const* d_in, const int* in_sizes, int n_in,
                              void* d_out, int out_size, void* d_ws, size_t ws_size,
                              hipStream_t stream) {
    const float* x     = (const float*)d_in[0];
    const float* c     = (const float*)d_in[1];
    const float* cond  = (const float*)d_in[2];
    const float* cosT  = (const float*)d_in[3];
    const float* sinT  = (const float*)d_in[4];
    const float* n1w   = (const float*)d_in[5];
    const float* n2w   = (const float*)d_in[6];
    const float* n3w   = (const float*)d_in[7];
    const float* cnw   = (const float*)d_in[8];
    const float* saqkvw  = (const float*)d_in[9];
    const float* saprojw = (const float*)d_in[10];
    const float* saprojb = (const float*)d_in[11];
    const float* saqnw   = (const float*)d_in[12];
    const float* saknw   = (const float*)d_in[13];
    const float* caqw    = (const float*)d_in[14];
    const float* cakw    = (const float*)d_in[15];
    const float* cavw    = (const float*)d_in[16];
    const float* caprojw = (const float*)d_in[17];
    const float* caprojb = (const float*)d_in[18];
    const float* caqnw   = (const float*)d_in[19];
    const float* caknw   = (const float*)d_in[20];
    const float* w1      = (const float*)d_in[21];
    const float* w2      = (const float*)d_in[22];
    const float* w3      = (const float*)d_in[23];
    const float* adaw    = (const float*)d_in[24];
    const float* adab    = (const float*)d_in[25];
    float* out = (float*)d_out;
    char* ws = (char*)d_ws;

    // ws layout (bytes):
    float* mod  = (float*)ws;                      // 0      : 27,648
    u16* hbuf   = (u16*)(ws + 32768);              // 32,768 : 3,145,728 (2048x768 bf16)
    u16* obuf   = (u16*)(ws + 3178496);            //         3,145,728
    char* R1    = ws + 6324224;                    // 12,582,912 shared region
    u16* qkvb   = (u16*)R1;                        //   qkv bf16 [2048][2304] (9,437,184)
    u16* vTb    = (u16*)(R1 + 9437184);            //   V^T bf16 [12][64][2048] (3,145,728)
    float* qbuf = (float*)R1;                      //   CA q f32 [2048][768]
    u16* gbuf   = (u16*)R1;                        //   MLP gate bf16 [2048][3072]
    float* cn   = (float*)(ws + 18907136);         // 49,152
    float* kca  = (float*)(ws + 18956288);         // 49,152
    float* vca  = (float*)(ws + 19005440);         // 49,152
    u16* wbuf   = (u16*)(ws + 19054592);           // 4,718,592 rotating bf16 weights
    // total 23,773,184 B

    ada_gemm<<<1728, 256, 0, stream>>>(c, adaw, adab, mod);

    // ---- self-attention ----
    rms_mod<<<2048, 256, 0, stream>>>(x, n1w, mod, 0, hbuf);
    cvt_bf16<<<864, 256, 0, stream>>>(saqkvw, wbuf, 221184);
    gemm_bt2<1><<<dim3(18, 16), 512, 0, stream>>>(hbuf, wbuf, 2048, 2304, 768,
                                                  nullptr, qkvb, nullptr, nullptr, nullptr);
    saqk_rmsrope<<<12288, 256, 0, stream>>>(qkvb, saqnw, saknw, cosT, sinT);
    v_transpose<<<dim3(32, 12), 256, 0, stream>>>(qkvb, vTb);
    sa_attn_mfma<<<dim3(32, 12), 256, 0, stream>>>(qkvb, vTb, obuf);
    cvt_bf16<<<288, 256, 0, stream>>>(saprojw, wbuf, 73728);
    gemm_bt2<2><<<dim3(6, 16), 512, 0, stream>>>(obuf, wbuf, 2048, 768, 768,
                                                 out, nullptr, x, mod + 2 * 768, saprojb);

    // ---- cross-attention ----
    rms_mod<<<2048, 256, 0, stream>>>(out, n2w, mod, 3, hbuf);
    cvt_bf16<<<288, 256, 0, stream>>>(caqw, wbuf, 73728);
    gemm_bt2<0><<<dim3(6, 16), 512, 0, stream>>>(hbuf, wbuf, 2048, 768, 768,
                                                 qbuf, nullptr, nullptr, nullptr, nullptr);
    rms_plain<<<16, 256, 0, stream>>>(cond, cnw, cn);
    small_gemm_nt<<<6144, 256, 0, stream>>>(cn, cakw, cavw, kca, vca);
    cak_rms<<<48, 256, 0, stream>>>(kca, caknw);
    caq_rmsrope<<<6144, 256, 0, stream>>>(qbuf, caqnw, cosT, sinT);
    ca_attn<<<6144, 256, 0, stream>>>(qbuf, kca, vca, obuf);
    cvt_bf16<<<288, 256, 0, stream>>>(caprojw, wbuf, 73728);
    gemm_bt2<2><<<dim3(6, 16), 512, 0, stream>>>(obuf, wbuf, 2048, 768, 768,
                                                 out, nullptr, out, mod + 5 * 768, caprojb);

    // ---- SwiGLU MLP ----
    rms_mod<<<2048, 256, 0, stream>>>(out, n3w, mod, 6, hbuf);
    cvt_bf16<<<1152, 256, 0, stream>>>(w1, wbuf, 294912);
    gemm_bt2<3><<<dim3(24, 16), 512, 0, stream>>>(hbuf, wbuf, 2048, 3072, 768,
                                                  nullptr, gbuf, nullptr, nullptr, nullptr);
    cvt_bf16<<<1152, 256, 0, stream>>>(w3, wbuf, 294912);
    gemm_bt2<4><<<dim3(24, 16), 512, 0, stream>>>(hbuf, wbuf, 2048, 3072, 768,
                                                  nullptr, gbuf, nullptr, nullptr, nullptr);
    cvt_bf16<<<1152, 256, 0, stream>>>(w2, wbuf, 294912);
    gemm_bt2<2><<<dim3(6, 16), 512, 0, stream>>>(gbuf, wbuf, 2048, 768, 3072,
                                                 out, nullptr, out, mod + 8 * 768, nullptr);
}

// Round 6
// 298.354 us; speedup vs baseline: 3.1006x; 1.1035x over previous
//
#include <hip/hip_runtime.h>

typedef unsigned short u16;
typedef unsigned int u32;
typedef __attribute__((ext_vector_type(8))) short s16x8;
typedef __attribute__((ext_vector_type(4))) float f32x4;
typedef __attribute__((ext_vector_type(4))) int i32x4;

// ---------- bf16 helpers (bit-level, RNE) ----------
static __device__ __forceinline__ float bf2f(u16 u) {
    return __uint_as_float(((u32)u) << 16);
}
static __device__ __forceinline__ u16 f2bf(float f) {
    u32 x = __float_as_uint(f);
    return (u16)((x + 0x7fffu + ((x >> 16) & 1u)) >> 16);
}
static __device__ __forceinline__ i32x4 pack8(float4 a, float4 b) {
    u32 p0 = (u32)f2bf(a.x) | ((u32)f2bf(a.y) << 16);
    u32 p1 = (u32)f2bf(a.z) | ((u32)f2bf(a.w) << 16);
    u32 p2 = (u32)f2bf(b.x) | ((u32)f2bf(b.y) << 16);
    u32 p3 = (u32)f2bf(b.z) | ((u32)f2bf(b.w) << 16);
    return (i32x4){(int)p0, (int)p1, (int)p2, (int)p3};
}
static __device__ __forceinline__ float wave_sum(float v) {
#pragma unroll
    for (int off = 32; off > 0; off >>= 1) v += __shfl_xor(v, off);
    return v;
}
// async global->LDS, 16B per lane; dest is wave-uniform base (+lane*16 by HW)
static __device__ __forceinline__ void gload16(const u16* g, void* l) {
    __builtin_amdgcn_global_load_lds((const __attribute__((address_space(1))) void*)g,
                                     (__attribute__((address_space(3))) void*)l, 16, 0, 0);
}

// ---------- fp32 -> bf16 weight conversion (8 elems/thread) ----------
__global__ __launch_bounds__(256) void cvt_bf16(const float* __restrict__ src,
                                                u16* __restrict__ dst, int n8) {
    int i = blockIdx.x * 256 + threadIdx.x;
    if (i >= n8) return;
    float4 a = *(const float4*)(src + (size_t)i * 8);
    float4 b = *(const float4*)(src + (size_t)i * 8 + 4);
    *(i32x4*)(dst + (size_t)i * 8) = pack8(a, b);
}

// ---------- adaLN: mod = silu(c) @ ada_w.T + ada_b ----------
__global__ __launch_bounds__(256) void ada_gemm(const float* __restrict__ c,
                                                const float* __restrict__ adaw,
                                                const float* __restrict__ adab,
                                                float* __restrict__ mod) {
    int wid = blockIdx.x * 4 + (threadIdx.x >> 6);
    int lane = threadIdx.x & 63;
    float sum = 0.f;
#pragma unroll
    for (int i = 0; i < 12; ++i) {
        float cv = c[i * 64 + lane];
        cv = cv / (1.f + __expf(-cv));
        sum += cv * adaw[(size_t)wid * 768 + i * 64 + lane];
    }
    sum = wave_sum(sum);
    if (lane == 0) mod[wid] = sum + adab[wid];
}

// ---------- fused RMSNorm + modulate, writes bf16 ----------
__global__ __launch_bounds__(256) void rms_mod(const float* __restrict__ x,
                                               const float* __restrict__ w,
                                               const float* __restrict__ mod, int chunk,
                                               u16* __restrict__ out) {
    const int row = blockIdx.x;
    const int tid = threadIdx.x;
    const float* xr = x + (size_t)row * 768;
    float v0 = xr[tid], v1 = xr[256 + tid], v2 = xr[512 + tid];
    float ss = wave_sum(v0 * v0 + v1 * v1 + v2 * v2);
    __shared__ float red[4];
    if ((tid & 63) == 0) red[tid >> 6] = ss;
    __syncthreads();
    float rn = rsqrtf((red[0] + red[1] + red[2] + red[3]) * (1.f / 768.f) + 1e-6f);
    const float* sh = mod + chunk * 768;
    const float* sc = sh + 768;
    u16* orow = out + (size_t)row * 768;
    orow[tid]       = f2bf(v0 * rn * w[tid]       * (1.f + sc[tid])       + sh[tid]);
    orow[256 + tid] = f2bf(v1 * rn * w[256 + tid] * (1.f + sc[256 + tid]) + sh[256 + tid]);
    orow[512 + tid] = f2bf(v2 * rn * w[512 + tid] * (1.f + sc[512 + tid]) + sh[512 + tid]);
}

// ---------- plain RMSNorm (cond), fp32 out ----------
__global__ __launch_bounds__(256) void rms_plain(const float* __restrict__ x,
                                                 const float* __restrict__ w,
                                                 float* __restrict__ out) {
    const int row = blockIdx.x;
    const int tid = threadIdx.x;
    const float* xr = x + (size_t)row * 768;
    float v0 = xr[tid], v1 = xr[256 + tid], v2 = xr[512 + tid];
    float ss = wave_sum(v0 * v0 + v1 * v1 + v2 * v2);
    __shared__ float red[4];
    if ((tid & 63) == 0) red[tid >> 6] = ss;
    __syncthreads();
    float rn = rsqrtf((red[0] + red[1] + red[2] + red[3]) * (1.f / 768.f) + 1e-6f);
    float* orow = out + (size_t)row * 768;
    orow[tid]       = v0 * rn * w[tid];
    orow[256 + tid] = v1 * rn * w[256 + tid];
    orow[512 + tid] = v2 * rn * w[512 + tid];
}

// ---------- MFMA bf16 GEMM, global_load_lds + 2-phase double buffer ----------
template <int EPI>
__global__ __launch_bounds__(512) void gemm_bt2(const u16* __restrict__ A,
                                                const u16* __restrict__ Wb,
                                                int M, int N, int K,
                                                float* outf, u16* outb,
                                                const float* resid,
                                                const float* __restrict__ gate,
                                                const float* __restrict__ bias) {
    __shared__ __align__(16) u16 As[2][128 * 64];
    __shared__ __align__(16) u16 Bs[2][128 * 64];
    const int tid = threadIdx.x;
    const int lane = tid & 63;
    const int w = tid >> 6;
    const int wr = w >> 2, wc = w & 3;  // 2x4 wave grid; per-wave 64x32 out
    const int row0 = blockIdx.y * 128, col0 = blockIdx.x * 128;

    const int r0u = tid >> 3, s0u = (tid & 7) ^ (r0u & 7);
    const int r1u = (tid + 512) >> 3, s1u = (tid & 7) ^ (r1u & 7);
    const u16* a0 = A + (size_t)(row0 + r0u) * K + s0u * 8;
    const u16* a1 = A + (size_t)(row0 + r1u) * K + s1u * 8;
    const u16* b0 = Wb + (size_t)(col0 + r0u) * K + s0u * 8;
    const u16* b1 = Wb + (size_t)(col0 + r1u) * K + s1u * 8;

    f32x4 acc[4][2];
#pragma unroll
    for (int m = 0; m < 4; ++m)
#pragma unroll
        for (int n = 0; n < 2; ++n) acc[m][n] = (f32x4){0.f, 0.f, 0.f, 0.f};

    const int nt = K >> 6;
    int cur = 0;
    {
        char* ad = (char*)As[0] + w * 1024;
        char* bd = (char*)Bs[0] + w * 1024;
        gload16(a0, ad);
        gload16(a1, ad + 8192);
        gload16(b0, bd);
        gload16(b1, bd + 8192);
    }
    for (int t = 0; t < nt; ++t) {
        __syncthreads();
        if (t + 1 < nt) {
            int k0 = (t + 1) << 6;
            char* ad = (char*)As[cur ^ 1] + w * 1024;
            char* bd = (char*)Bs[cur ^ 1] + w * 1024;
            gload16(a0 + k0, ad);
            gload16(a1 + k0, ad + 8192);
            gload16(b0 + k0, bd);
            gload16(b1 + k0, bd + 8192);
        }
#pragma unroll
        for (int kk = 0; kk < 2; ++kk) {
            s16x8 af[4], bfv[2];
#pragma unroll
            for (int m = 0; m < 4; ++m) {
                int ra = wr * 64 + m * 16 + (lane & 15);
                int u = (kk * 4 + (lane >> 4)) ^ (ra & 7);
                af[m] = *(const s16x8*)((const char*)As[cur] + ra * 128 + u * 16);
            }
#pragma unroll
            for (int n = 0; n < 2; ++n) {
                int cb = wc * 32 + n * 16 + (lane & 15);
                int u = (kk * 4 + (lane >> 4)) ^ (cb & 7);
                bfv[n] = *(const s16x8*)((const char*)Bs[cur] + cb * 128 + u * 16);
            }
#pragma unroll
            for (int m = 0; m < 4; ++m)
#pragma unroll
                for (int n = 0; n < 2; ++n)
                    acc[m][n] = __builtin_amdgcn_mfma_f32_16x16x32_bf16(af[m], bfv[n], acc[m][n], 0, 0, 0);
        }
        cur ^= 1;
    }
#pragma unroll
    for (int m = 0; m < 4; ++m) {
#pragma unroll
        for (int n = 0; n < 2; ++n) {
#pragma unroll
            for (int i = 0; i < 4; ++i) {
                int r = row0 + wr * 64 + m * 16 + (lane >> 4) * 4 + i;
                int cc = col0 + wc * 32 + n * 16 + (lane & 15);
                size_t idx = (size_t)r * N + cc;
                float v = acc[m][n][i];
                if constexpr (EPI == 0) {
                    outf[idx] = v;
                } else if constexpr (EPI == 1) {
                    outb[idx] = f2bf(v);
                } else if constexpr (EPI == 2) {
                    float b = bias ? bias[cc] : 0.f;
                    outf[idx] = resid[idx] + gate[cc] * (v + b);
                } else if constexpr (EPI == 3) {
                    outb[idx] = f2bf(v / (1.f + __expf(-v)));
                } else if constexpr (EPI == 4) {
                    outb[idx] = f2bf(v * bf2f(outb[idx]));
                }
            }
        }
    }
}

// ---------- SA q/k: RMSNorm(head) + RoPE, in place on qkv bf16 ----------
__global__ __launch_bounds__(256) void saqk_rmsrope(u16* __restrict__ qkv,
                                                    const float* __restrict__ qnw,
                                                    const float* __restrict__ knw,
                                                    const float* __restrict__ cosT,
                                                    const float* __restrict__ sinT) {
    int wid = blockIdx.x * 4 + (threadIdx.x >> 6);  // 0..49151
    int lane = threadIdx.x & 63;
    int n = wid / 24;
    int rem = wid % 24;
    int which = rem / 12;  // 0=q 1=k
    int h = rem % 12;
    u16* p = qkv + (size_t)n * 2304 + which * 768 + h * 64 + lane;
    float v = bf2f(*p);
    float ss = wave_sum(v * v);
    const float* wv = which ? knw : qnw;
    float vn = v * rsqrtf(ss * (1.f / 64.f) + 1e-6f) * wv[lane];
    float part = __shfl_xor(vn, 32);
    float rot = (lane < 32) ? -part : part;
    *p = f2bf(vn * cosT[n * 64 + lane] + rot * sinT[n * 64 + lane]);
}

// ---------- V transpose: qkv V part [2048][12*64] -> vT [12][64][2048] ----------
__global__ __launch_bounds__(256) void v_transpose(const u16* __restrict__ qkv,
                                                   u16* __restrict__ vT) {
    const int kt = blockIdx.x, h = blockIdx.y;
    const int tid = threadIdx.x;
    __shared__ __align__(16) u16 tt[64][72];  // +8 pad breaks bank conflicts
    {
        int key = tid >> 2, qq = tid & 3;
        const u16* src = qkv + (size_t)(kt * 64 + key) * 2304 + 1536 + h * 64 + qq * 16;
        *(i32x4*)&tt[key][qq * 16]     = *(const i32x4*)src;
        *(i32x4*)&tt[key][qq * 16 + 8] = *(const i32x4*)(src + 8);
    }
    __syncthreads();
    {
        int d = tid >> 2, kq = tid & 3;
        s16x8 o0, o1;
#pragma unroll
        for (int e = 0; e < 8; ++e) o0[e] = (short)tt[kq * 16 + e][d];
#pragma unroll
        for (int e = 0; e < 8; ++e) o1[e] = (short)tt[kq * 16 + 8 + e][d];
        u16* dst = vT + (size_t)h * 131072 + (size_t)d * 2048 + kt * 64 + kq * 16;
        *(s16x8*)dst = o0;
        *(s16x8*)(dst + 8) = o1;
    }
}

// ---------- SA flash attention, MFMA bf16, FIXED-MAX softmax + 2-way key split ----------
// grid (32 qblocks, 12 heads, 2 key-splits); 4 waves x 16 q rows; 16 tiles of 64 keys.
// Scores bounded: |q.k|/8 <= 8 (unit-RMS q,k; RoPE norm-preserving) -> p = exp(s/8 - 8)
// needs no running max, so partials are additive across splits.
// Writes unnormalized O_partial (bf16) and per-row l (f32); sa_combine merges.
__global__ __launch_bounds__(256) void sa_attn_mfma(const u16* __restrict__ qkv,
                                                    const u16* __restrict__ vT,
                                                    u16* __restrict__ po0,
                                                    u16* __restrict__ po1,
                                                    float* __restrict__ pl) {
    const int h = blockIdx.y;
    const int r0 = blockIdx.x * 64;
    const int z = blockIdx.z;  // key split
    const int tid = threadIdx.x;
    const int lane = tid & 63;
    const int w = tid >> 6;
    __shared__ __align__(16) u16 Ks[2][64 * 64];
    __shared__ __align__(16) u16 Vs[2][64 * 64];
    __shared__ __align__(16) u16 Ps[4][16 * 64];

    // Q fragments (A-operand), unscaled; 1/8 folded into exp argument
    s16x8 qf[2];
    {
        const u16* qrow = qkv + (size_t)(r0 + w * 16 + (lane & 15)) * 2304 + h * 64 + ((lane >> 4) * 8);
        qf[0] = *(const s16x8*)qrow;
        qf[1] = *(const s16x8*)(qrow + 32);
    }
    f32x4 oacc[4];
#pragma unroll
    for (int n = 0; n < 4; ++n) oacc[n] = (f32x4){0.f, 0.f, 0.f, 0.f};
    float lp[4] = {0.f, 0.f, 0.f, 0.f};

    // staging source pointers; wave w stages 16B-units (w*2+j)*64+lane of each tile
    const u16* ksrc[2];
    const u16* vsrc[2];
#pragma unroll
    for (int j = 0; j < 2; ++j) {
        int u = (w * 2 + j) * 64 + lane;
        int row = u >> 3, seg = (u & 7) ^ (row & 7);
        ksrc[j] = qkv + (size_t)(z * 1024 + row) * 2304 + 768 + h * 64 + seg * 8;      // K[key=row]
        vsrc[j] = vT + (size_t)h * 131072 + (size_t)row * 2048 + z * 1024 + seg * 8;   // V^T[d=row]
    }

#define SA_STAGE(buf, t_)                                          \
    {                                                              \
        char* kd = (char*)Ks[buf] + w * 2048;                      \
        char* vd = (char*)Vs[buf] + w * 2048;                      \
        gload16(ksrc[0] + (size_t)(t_) * 147456, kd);              \
        gload16(ksrc[1] + (size_t)(t_) * 147456, kd + 1024);       \
        gload16(vsrc[0] + (t_) * 64, vd);                          \
        gload16(vsrc[1] + (t_) * 64, vd + 1024);                   \
    }

    SA_STAGE(0, 0)
    int cur = 0;
    for (int t = 0; t < 16; ++t) {
        __syncthreads();  // drains vmcnt: tile t staged; buf cur^1 free
        if (t + 1 < 16) SA_STAGE(cur ^ 1, t + 1)

        // ---- QK^T: S[16 rows][64 keys] per wave ----
        f32x4 sacc[4];
#pragma unroll
        for (int n = 0; n < 4; ++n) sacc[n] = (f32x4){0.f, 0.f, 0.f, 0.f};
#pragma unroll
        for (int kk = 0; kk < 2; ++kk) {
#pragma unroll
            for (int n = 0; n < 4; ++n) {
                int key = n * 16 + (lane & 15);
                int d = kk * 32 + (lane >> 4) * 8;
                int boff = key * 128 + ((d * 2) ^ ((key & 7) << 4));
                s16x8 kf = *(const s16x8*)((const char*)Ks[cur] + boff);
                sacc[n] = __builtin_amdgcn_mfma_f32_16x16x32_bf16(qf[kk], kf, sacc[n], 0, 0, 0);
            }
        }
        // ---- fixed-max softmax: p = exp(s*0.125 - 8), no max tracking ----
#pragma unroll
        for (int n = 0; n < 4; ++n) {
#pragma unroll
            for (int i = 0; i < 4; ++i) {
                float p = __expf(fmaf(sacc[n][i], 0.125f, -8.0f));
                lp[i] += p;
                int row = (lane >> 4) * 4 + i;
                int key = n * 16 + (lane & 15);
                int boff = row * 128 + ((key * 2) ^ ((row & 7) << 4));
                *(u16*)((char*)Ps[w] + boff) = f2bf(p);
            }
        }
        // ---- PV: O[16q][64d] += P[16q][64k] @ V[64k][64d]  (B-frag from V^T tile) ----
#pragma unroll
        for (int kk = 0; kk < 2; ++kk) {
            int koff = kk * 32 + (lane >> 4) * 8;
            int prow = lane & 15;
            int pboff = prow * 128 + ((koff * 2) ^ ((prow & 7) << 4));
            s16x8 pf = *(const s16x8*)((const char*)Ps[w] + pboff);
#pragma unroll
            for (int n = 0; n < 4; ++n) {
                int d = n * 16 + (lane & 15);
                int vboff = d * 128 + ((koff * 2) ^ ((d & 7) << 4));
                s16x8 vf = *(const s16x8*)((const char*)Vs[cur] + vboff);
                oacc[n] = __builtin_amdgcn_mfma_f32_16x16x32_bf16(pf, vf, oacc[n], 0, 0, 0);
            }
        }
        cur ^= 1;
    }
#undef SA_STAGE
    // row-sum reduce across 16-lane group; store unnormalized partials
#pragma unroll
    for (int off = 1; off < 16; off <<= 1) {
#pragma unroll
        for (int i = 0; i < 4; ++i) lp[i] += __shfl_xor(lp[i], off);
    }
    u16* po = z ? po1 : po0;
#pragma unroll
    for (int n = 0; n < 4; ++n) {
#pragma unroll
        for (int i = 0; i < 4; ++i) {
            int r = r0 + w * 16 + (lane >> 4) * 4 + i;
            int d = n * 16 + (lane & 15);
            po[(size_t)r * 768 + h * 64 + d] = f2bf(oacc[n][i]);
        }
    }
    if ((lane & 15) == 0) {
#pragma unroll
        for (int i = 0; i < 4; ++i) {
            int r = r0 + w * 16 + (lane >> 4) * 4 + i;
            pl[z * 24576 + h * 2048 + r] = lp[i];
        }
    }
}

// ---------- combine the two key-split partials: O = (Oa+Ob)/(la+lb) ----------
__global__ __launch_bounds__(256) void sa_combine(const u16* __restrict__ pa,
                                                  const u16* __restrict__ pb,
                                                  const float* __restrict__ pl,
                                                  u16* __restrict__ obuf) {
    int idx = blockIdx.x * 256 + threadIdx.x;  // 8-elem units; 196608 total
    int base = idx * 8;
    int row = base / 768;
    int col = base % 768;
    int h = col >> 6;
    float inv = 1.f / (pl[h * 2048 + row] + pl[24576 + h * 2048 + row]);
    s16x8 a = *(const s16x8*)(pa + base);
    s16x8 b = *(const s16x8*)(pb + base);
    s16x8 o;
#pragma unroll
    for (int e = 0; e < 8; ++e)
        o[e] = (short)f2bf((bf2f((u16)a[e]) + bf2f((u16)b[e])) * inv);
    *(s16x8*)(obuf + base) = o;
}

// ---------- CA attention ----------
__global__ __launch_bounds__(256) void ca_attn(const float* __restrict__ qb,
                                               const float* __restrict__ kca,
                                               const float* __restrict__ vca,
                                               u16* __restrict__ obuf) {
    int wid = blockIdx.x * 4 + (threadIdx.x >> 6);
    int lane = threadIdx.x & 63;
    int n = wid / 12, h = wid % 12;
    float qd = qb[(size_t)n * 768 + h * 64 + lane] * 0.125f;
    float s[16];
#pragma unroll
    for (int j = 0; j < 16; ++j) {
        float part = qd * kca[(size_t)j * 768 + h * 64 + lane];
        s[j] = wave_sum(part);
    }
    float mm = s[0];
#pragma unroll
    for (int j = 1; j < 16; ++j) mm = fmaxf(mm, s[j]);
    float l = 0.f;
#pragma unroll
    for (int j = 0; j < 16; ++j) { s[j] = __expf(s[j] - mm); l += s[j]; }
    float od = 0.f;
#pragma unroll
    for (int j = 0; j < 16; ++j) od += s[j] * vca[(size_t)j * 768 + h * 64 + lane];
    obuf[(size_t)n * 768 + h * 64 + lane] = f2bf(od / l);
}

// ---------- CA q: RMSNorm + RoPE in place on qbuf f32 [2048][768] ----------
__global__ __launch_bounds__(256) void caq_rmsrope(float* __restrict__ qb,
                                                   const float* __restrict__ qnw,
                                                   const float* __restrict__ cosT,
                                                   const float* __restrict__ sinT) {
    int wid = blockIdx.x * 4 + (threadIdx.x >> 6);
    int lane = threadIdx.x & 63;
    int n = wid / 12, h = wid % 12;
    float* p = qb + (size_t)n * 768 + h * 64 + lane;
    float v = *p;
    float ss = wave_sum(v * v);
    float vn = v * rsqrtf(ss * (1.f / 64.f) + 1e-6f) * qnw[lane];
    float part = __shfl_xor(vn, 32);
    float rot = (lane < 32) ? -part : part;
    *p = vn * cosT[n * 64 + lane] + rot * sinT[n * 64 + lane];
}

// ---------- CA k: RMSNorm only, in place on kca [16][768] ----------
__global__ __launch_bounds__(256) void cak_rms(float* __restrict__ kca,
                                               const float* __restrict__ knw) {
    int wid = blockIdx.x * 4 + (threadIdx.x >> 6);  // 0..191
    int lane = threadIdx.x & 63;
    int n = wid / 12, h = wid % 12;
    float* p = kca + (size_t)n * 768 + h * 64 + lane;
    float v = *p;
    float ss = wave_sum(v * v);
    *p = v * rsqrtf(ss * (1.f / 64.f) + 1e-6f) * knw[lane];
}

// ---------- CA k/v small GEMM: [16,768] = cn[16,768] @ W[768,768]^T ----------
__global__ __launch_bounds__(256) void small_gemm_nt(const float* __restrict__ cn,
                                                     const float* __restrict__ cakw,
                                                     const float* __restrict__ cavw,
                                                     float* __restrict__ kca,
                                                     float* __restrict__ vca) {
    int wid = blockIdx.x * 4 + (threadIdx.x >> 6);  // 0..24575
    int lane = threadIdx.x & 63;
    int which = wid / 12288;
    int rem = wid % 12288;
    int rrow = rem / 768;
    int ocol = rem % 768;
    const float* Wm = which ? cavw : cakw;
    float sum = 0.f;
#pragma unroll
    for (int i = 0; i < 12; ++i)
        sum += cn[(size_t)rrow * 768 + i * 64 + lane] * Wm[(size_t)ocol * 768 + i * 64 + lane];
    sum = wave_sum(sum);
    if (lane == 0) (which ? vca : kca)[(size_t)rrow * 768 + ocol] = sum;
}

// =======================================================================
extern "C" void kernel_launch(void* const* d_in, const int* in_sizes, int n_in,
                              void* d_out, int out_size, void* d_ws, size_t ws_size,
                              hipStream_t stream) {
    const float* x     = (const float*)d_in[0];
    const float* c     = (const float*)d_in[1];
    const float* cond  = (const float*)d_in[2];
    const float* cosT  = (const float*)d_in[3];
    const float* sinT  = (const float*)d_in[4];
    const float* n1w   = (const float*)d_in[5];
    const float* n2w   = (const float*)d_in[6];
    const float* n3w   = (const float*)d_in[7];
    const float* cnw   = (const float*)d_in[8];
    const float* saqkvw  = (const float*)d_in[9];
    const float* saprojw = (const float*)d_in[10];
    const float* saprojb = (const float*)d_in[11];
    const float* saqnw   = (const float*)d_in[12];
    const float* saknw   = (const float*)d_in[13];
    const float* caqw    = (const float*)d_in[14];
    const float* cakw    = (const float*)d_in[15];
    const float* cavw    = (const float*)d_in[16];
    const float* caprojw = (const float*)d_in[17];
    const float* caprojb = (const float*)d_in[18];
    const float* caqnw   = (const float*)d_in[19];
    const float* caknw   = (const float*)d_in[20];
    const float* w1      = (const float*)d_in[21];
    const float* w2      = (const float*)d_in[22];
    const float* w3      = (const float*)d_in[23];
    const float* adaw    = (const float*)d_in[24];
    const float* adab    = (const float*)d_in[25];
    float* out = (float*)d_out;
    char* ws = (char*)d_ws;

    // ws layout (bytes):
    float* mod  = (float*)ws;                      // 0      : 27,648
    u16* hbuf   = (u16*)(ws + 32768);              // 32,768 : 3,145,728 (2048x768 bf16)
    u16* obuf   = (u16*)(ws + 3178496);            //         3,145,728
    char* R1    = ws + 6324224;                    // 12,582,912 shared region
    u16* qkvb   = (u16*)R1;                        //   qkv bf16 [2048][2304] (9,437,184)
    u16* vTb    = (u16*)(R1 + 9437184);            //   V^T bf16 [12][64][2048] (3,145,728)
    float* qbuf = (float*)R1;                      //   CA q f32 [2048][768]
    u16* gbuf   = (u16*)R1;                        //   MLP gate bf16 [2048][3072]
    float* cn   = (float*)(ws + 18907136);         // 49,152
    float* kca  = (float*)(ws + 18956288);         // 49,152
    float* vca  = (float*)(ws + 19005440);         // 49,152
    u16* wbuf   = (u16*)(ws + 19054592);           // 4,718,592 rotating bf16 weights
    // attention partials (transient, reuse hbuf + wbuf):
    u16* po0    = hbuf;                            // split-0 unnormalized O (3,145,728)
    u16* po1    = wbuf;                            // split-1 unnormalized O (3,145,728)
    float* plb  = (float*)(ws + 22200320);         // l partials [2][12][2048] f32 (196,608)
    // total 23,773,184 B

    ada_gemm<<<1728, 256, 0, stream>>>(c, adaw, adab, mod);

    // ---- self-attention ----
    rms_mod<<<2048, 256, 0, stream>>>(x, n1w, mod, 0, hbuf);
    cvt_bf16<<<864, 256, 0, stream>>>(saqkvw, wbuf, 221184);
    gemm_bt2<1><<<dim3(18, 16), 512, 0, stream>>>(hbuf, wbuf, 2048, 2304, 768,
                                                  nullptr, qkvb, nullptr, nullptr, nullptr);
    saqk_rmsrope<<<12288, 256, 0, stream>>>(qkvb, saqnw, saknw, cosT, sinT);
    v_transpose<<<dim3(32, 12), 256, 0, stream>>>(qkvb, vTb);
    sa_attn_mfma<<<dim3(32, 12, 2), 256, 0, stream>>>(qkvb, vTb, po0, po1, plb);
    sa_combine<<<768, 256, 0, stream>>>(po0, po1, plb, obuf);
    cvt_bf16<<<288, 256, 0, stream>>>(saprojw, wbuf, 73728);
    gemm_bt2<2><<<dim3(6, 16), 512, 0, stream>>>(obuf, wbuf, 2048, 768, 768,
                                                 out, nullptr, x, mod + 2 * 768, saprojb);

    // ---- cross-attention ----
    rms_mod<<<2048, 256, 0, stream>>>(out, n2w, mod, 3, hbuf);
    cvt_bf16<<<288, 256, 0, stream>>>(caqw, wbuf, 73728);
    gemm_bt2<0><<<dim3(6, 16), 512, 0, stream>>>(hbuf, wbuf, 2048, 768, 768,
                                                 qbuf, nullptr, nullptr, nullptr, nullptr);
    rms_plain<<<16, 256, 0, stream>>>(cond, cnw, cn);
    small_gemm_nt<<<6144, 256, 0, stream>>>(cn, cakw, cavw, kca, vca);
    cak_rms<<<48, 256, 0, stream>>>(kca, caknw);
    caq_rmsrope<<<6144, 256, 0, stream>>>(qbuf, caqnw, cosT, sinT);
    ca_attn<<<6144, 256, 0, stream>>>(qbuf, kca, vca, obuf);
    cvt_bf16<<<288, 256, 0, stream>>>(caprojw, wbuf, 73728);
    gemm_bt2<2><<<dim3(6, 16), 512, 0, stream>>>(obuf, wbuf, 2048, 768, 768,
                                                 out, nullptr, out, mod + 5 * 768, caprojb);

    // ---- SwiGLU MLP ----
    rms_mod<<<2048, 256, 0, stream>>>(out, n3w, mod, 6, hbuf);
    cvt_bf16<<<1152, 256, 0, stream>>>(w1, wbuf, 294912);
    gemm_bt2<3><<<dim3(24, 16), 512, 0, stream>>>(hbuf, wbuf, 2048, 3072, 768,
                                                  nullptr, gbuf, nullptr, nullptr, nullptr);
    cvt_bf16<<<1152, 256, 0, stream>>>(w3, wbuf, 294912);
    gemm_bt2<4><<<dim3(24, 16), 512, 0, stream>>>(hbuf, wbuf, 2048, 3072, 768,
                                                  nullptr, gbuf, nullptr, nullptr, nullptr);
    cvt_bf16<<<1152, 256, 0, stream>>>(w2, wbuf, 294912);
    gemm_bt2<2><<<dim3(6, 16), 512, 0, stream>>>(gbuf, wbuf, 2048, 768, 3072,
                                                 out, nullptr, out, mod + 8 * 768, nullptr);
}